// Round 1
// baseline (2074.676 us; speedup 1.0000x reference)
//
#include <hip/hip_runtime.h>
#include <hip/hip_bf16.h>
#include <math.h>

// Problem constants (Swin block: B=8, H=W=56, C=384, ws=7, nh=12)
#define T_TOK 25088   // B * L
#define L_DIM 3136
#define C_DIM 384
#define NHEADS 12
#define HDIM 32
#define NWIN 512      // B * 8 * 8
#define NTOK 49       // ws*ws

__device__ __forceinline__ float gelu_exact(float x) {
    return 0.5f * x * (1.0f + erff(x * 0.70710678118654752440f));
}

// ---------------------------------------------------------------------------
// LayerNorm, one wave (64 lanes) per token row of 384.
// WINDOWED=true scatters output into window-partition layout (Bw*49, C).
// ---------------------------------------------------------------------------
template<bool WINDOWED>
__global__ __launch_bounds__(256) void ln_kernel(
    const float* __restrict__ x, const float* __restrict__ g,
    const float* __restrict__ b, float* __restrict__ y)
{
    int gid  = blockIdx.x * 256 + threadIdx.x;
    int t    = gid >> 6;
    int lane = threadIdx.x & 63;
    if (t >= T_TOK) return;

    const float* row = x + (size_t)t * C_DIM;
    float vals[6];
    float s = 0.f, s2 = 0.f;
#pragma unroll
    for (int i = 0; i < 6; ++i) {
        float v = row[lane + i * 64];
        vals[i] = v; s += v; s2 += v * v;
    }
#pragma unroll
    for (int off = 32; off; off >>= 1) {
        s  += __shfl_down(s, off);
        s2 += __shfl_down(s2, off);
    }
    s  = __shfl(s, 0);
    s2 = __shfl(s2, 0);
    float mean = s * (1.0f / C_DIM);
    float var  = s2 * (1.0f / C_DIM) - mean * mean;
    float rstd = rsqrtf(var + 1e-5f);

    float* outrow;
    if (WINDOWED) {
        int bb = t / L_DIM, l = t % L_DIM;
        int hr = l / 56, wc = l % 56;
        int w  = (bb * 8 + hr / 7) * 8 + wc / 7;
        int n  = (hr % 7) * 7 + (wc % 7);
        outrow = y + ((size_t)w * NTOK + n) * C_DIM;
    } else {
        outrow = y + (size_t)t * C_DIM;
    }
#pragma unroll
    for (int i = 0; i < 6; ++i) {
        int c = lane + i * 64;
        outrow[c] = (vals[i] - mean) * rstd * g[c] + b[c];
    }
}

// ---------------------------------------------------------------------------
// Tiled fp32 GEMM: Y[M x Nn] = X[M x K] @ W[Nn x K]^T  (torch Linear layout)
// 64x64 tile, BK=16, 256 threads, 4x4 accum per thread.
// EPI: 0=none, 1=+bias, 2=gelu(y+bias), 3=res + ls*(y+bias)
// M % 64 == 0, Nn % 64 == 0, K % 16 == 0 assumed (holds for all uses).
// ---------------------------------------------------------------------------
template<int EPI>
__global__ __launch_bounds__(256) void gemm_kernel(
    const float* __restrict__ X, const float* __restrict__ W,
    const float* __restrict__ bias, const float* __restrict__ res,
    const float* __restrict__ ls, float* __restrict__ Y,
    int M, int Nn, int K)
{
    __shared__ float As[64][17];
    __shared__ float Bs[16][65];

    int tid = threadIdx.x;
    int m0 = blockIdx.x * 64, n0 = blockIdx.y * 64;
    int ty = tid >> 4, tx = tid & 15;
    int ar = tid >> 2, ac = (tid & 3) << 2;

    float acc[4][4] = {};

    for (int k0 = 0; k0 < K; k0 += 16) {
        float4 av = *(const float4*)(X + (size_t)(m0 + ar) * K + k0 + ac);
        float4 bv = *(const float4*)(W + (size_t)(n0 + ar) * K + k0 + ac);
        As[ar][ac + 0] = av.x; As[ar][ac + 1] = av.y;
        As[ar][ac + 2] = av.z; As[ar][ac + 3] = av.w;
        Bs[ac + 0][ar] = bv.x; Bs[ac + 1][ar] = bv.y;
        Bs[ac + 2][ar] = bv.z; Bs[ac + 3][ar] = bv.w;
        __syncthreads();
#pragma unroll
        for (int kk = 0; kk < 16; ++kk) {
            float a0 = As[ty * 4 + 0][kk], a1 = As[ty * 4 + 1][kk];
            float a2 = As[ty * 4 + 2][kk], a3 = As[ty * 4 + 3][kk];
            float b0 = Bs[kk][tx * 4 + 0], b1 = Bs[kk][tx * 4 + 1];
            float b2 = Bs[kk][tx * 4 + 2], b3 = Bs[kk][tx * 4 + 3];
            acc[0][0] += a0 * b0; acc[0][1] += a0 * b1; acc[0][2] += a0 * b2; acc[0][3] += a0 * b3;
            acc[1][0] += a1 * b0; acc[1][1] += a1 * b1; acc[1][2] += a1 * b2; acc[1][3] += a1 * b3;
            acc[2][0] += a2 * b0; acc[2][1] += a2 * b1; acc[2][2] += a2 * b2; acc[2][3] += a2 * b3;
            acc[3][0] += a3 * b0; acc[3][1] += a3 * b1; acc[3][2] += a3 * b2; acc[3][3] += a3 * b3;
        }
        __syncthreads();
    }

    int col = n0 + tx * 4;
#pragma unroll
    for (int i = 0; i < 4; ++i) {
        int row = m0 + ty * 4 + i;
        float4 v = make_float4(acc[i][0], acc[i][1], acc[i][2], acc[i][3]);
        if (EPI >= 1) {
            v.x += bias[col + 0]; v.y += bias[col + 1];
            v.z += bias[col + 2]; v.w += bias[col + 3];
        }
        if (EPI == 2) {
            v.x = gelu_exact(v.x); v.y = gelu_exact(v.y);
            v.z = gelu_exact(v.z); v.w = gelu_exact(v.w);
        }
        if (EPI == 3) {
            float4 r4 = *(const float4*)(res + (size_t)row * Nn + col);
            v.x = r4.x + ls[col + 0] * v.x;
            v.y = r4.y + ls[col + 1] * v.y;
            v.z = r4.z + ls[col + 2] * v.z;
            v.w = r4.w + ls[col + 3] * v.w;
        }
        *(float4*)(Y + (size_t)row * Nn + col) = v;
    }
}

// ---------------------------------------------------------------------------
// Windowed attention: one block per (window, head). N=49, hd=32.
// q: (Bw*49, 384) window layout; kv: (Bw*49, 768): k at col h*32+d, v at +384.
// Relative-position bias index computed inline.
// ---------------------------------------------------------------------------
__global__ __launch_bounds__(256) void attn_kernel(
    const float* __restrict__ q, const float* __restrict__ kv,
    const float* __restrict__ bias_table, float* __restrict__ o)
{
    __shared__ float qs[NTOK][33];
    __shared__ float ks[NTOK][33];
    __shared__ float vs[NTOK][33];
    __shared__ float ss[NTOK][50];

    int w = blockIdx.x / NHEADS;
    int h = blockIdx.x % NHEADS;
    int tid = threadIdx.x;

    for (int e = tid; e < NTOK * 32; e += 256) {
        int n = e >> 5, d = e & 31;
        size_t qoff = ((size_t)w * NTOK + n) * C_DIM + h * HDIM + d;
        size_t koff = ((size_t)w * NTOK + n) * (2 * C_DIM) + h * HDIM + d;
        qs[n][d] = q[qoff];
        ks[n][d] = kv[koff];
        vs[n][d] = kv[koff + C_DIM];
    }
    __syncthreads();

    const float scale = 0.17677669529663687f;  // 1/sqrt(32)
    for (int e = tid; e < NTOK * NTOK; e += 256) {
        int n = e / NTOK, m = e % NTOK;
        float acc = 0.f;
#pragma unroll
        for (int kk = 0; kk < 32; ++kk) acc += qs[n][kk] * ks[m][kk];
        int i1 = n / 7, j1 = n % 7, i2 = m / 7, j2 = m % 7;
        int idx = (i1 - i2 + 6) * 13 + (j1 - j2 + 6);
        ss[n][m] = acc * scale + bias_table[idx * NHEADS + h];
    }
    __syncthreads();

    // softmax: wave per row
    int wv = tid >> 6, lane = tid & 63;
    for (int r = wv; r < NTOK; r += 4) {
        float v = (lane < NTOK) ? ss[r][lane] : -INFINITY;
        float mx = v;
#pragma unroll
        for (int off = 32; off; off >>= 1) mx = fmaxf(mx, __shfl_down(mx, off));
        mx = __shfl(mx, 0);
        float ev = (lane < NTOK) ? expf(v - mx) : 0.f;
        float sum = ev;
#pragma unroll
        for (int off = 32; off; off >>= 1) sum += __shfl_down(sum, off);
        sum = __shfl(sum, 0);
        if (lane < NTOK) ss[r][lane] = ev / sum;
    }
    __syncthreads();

    for (int e = tid; e < NTOK * 32; e += 256) {
        int n = e >> 5, d = e & 31;
        float acc = 0.f;
#pragma unroll
        for (int m = 0; m < NTOK; ++m) acc += ss[n][m] * vs[m][d];
        o[((size_t)w * NTOK + n) * C_DIM + h * HDIM + d] = acc;
    }
}

// ---------------------------------------------------------------------------
// Window reverse + residual + layer-scale:
// out[b,l,c] = x[b,l,c] + ls1[c] * p[windowrow(b,l), c]   (float4 per thread)
// ---------------------------------------------------------------------------
__global__ __launch_bounds__(256) void reverse_residual_kernel(
    const float* __restrict__ x, const float* __restrict__ p,
    const float* __restrict__ ls1, float* __restrict__ out)
{
    int idx = blockIdx.x * 256 + threadIdx.x;  // over T_TOK * 96
    int t = idx / 96;
    int c = (idx % 96) * 4;
    if (t >= T_TOK) return;
    int bb = t / L_DIM, l = t % L_DIM;
    int hr = l / 56, wc = l % 56;
    int w = (bb * 8 + hr / 7) * 8 + wc / 7;
    int n = (hr % 7) * 7 + (wc % 7);
    float4 pv = *(const float4*)(p + ((size_t)w * NTOK + n) * C_DIM + c);
    float4 xv = *(const float4*)(x + (size_t)t * C_DIM + c);
    float4 lv = *(const float4*)(ls1 + c);
    float4 ov;
    ov.x = xv.x + lv.x * pv.x;
    ov.y = xv.y + lv.y * pv.y;
    ov.z = xv.z + lv.z * pv.z;
    ov.w = xv.w + lv.w * pv.w;
    *(float4*)(out + (size_t)t * C_DIM + c) = ov;
}

// ---------------------------------------------------------------------------
extern "C" void kernel_launch(void* const* d_in, const int* in_sizes, int n_in,
                              void* d_out, int out_size, void* d_ws, size_t ws_size,
                              hipStream_t stream)
{
    const float* x       = (const float*)d_in[0];
    const float* q_w     = (const float*)d_in[1];
    const float* kv_w    = (const float*)d_in[2];
    const float* proj_w  = (const float*)d_in[3];
    const float* proj_b  = (const float*)d_in[4];
    const float* fc1_w   = (const float*)d_in[5];
    const float* fc1_b   = (const float*)d_in[6];
    const float* fc2_w   = (const float*)d_in[7];
    const float* fc2_b   = (const float*)d_in[8];
    const float* n1g     = (const float*)d_in[9];
    const float* n1b     = (const float*)d_in[10];
    const float* n2g     = (const float*)d_in[11];
    const float* n2b     = (const float*)d_in[12];
    const float* ls1     = (const float*)d_in[13];
    const float* ls2     = (const float*)d_in[14];
    const float* btable  = (const float*)d_in[15];

    float* out = (float*)d_out;
    char*  ws  = (char*)d_ws;

    // Workspace layout (192.7 MB total):
    //   slotA: 38.5 MB  — q  -> proj_out -> ln2_out
    //   big:   154  MB  — [xw (38.5) | kv (77)] -> mlp hidden (154)
    const size_t SZ = (size_t)T_TOK * C_DIM * sizeof(float);  // 38,535,168
    float* slotA  = (float*)ws;
    float* big    = (float*)(ws + SZ);
    float* xw     = big;
    float* kvbuf  = big + (size_t)T_TOK * C_DIM;
    float* hidden = big;
    float* obuf   = xw;     // attention output overwrites xw
    float* pbuf   = slotA;  // proj output overwrites q
    float* hbuf   = slotA;  // ln2 output overwrites proj output

    // 1. LN1 + window partition  (x -> xw)
    ln_kernel<true><<<(T_TOK * 64 + 255) / 256, 256, 0, stream>>>(x, n1g, n1b, xw);

    // 2. q = xw @ q_w^T ; kv = xw @ kv_w^T
    gemm_kernel<0><<<dim3(T_TOK / 64, C_DIM / 64), 256, 0, stream>>>(
        xw, q_w, nullptr, nullptr, nullptr, slotA, T_TOK, C_DIM, C_DIM);
    gemm_kernel<0><<<dim3(T_TOK / 64, 2 * C_DIM / 64), 256, 0, stream>>>(
        xw, kv_w, nullptr, nullptr, nullptr, kvbuf, T_TOK, 2 * C_DIM, C_DIM);

    // 3. windowed attention  (q, kv -> o)
    attn_kernel<<<NWIN * NHEADS, 256, 0, stream>>>(slotA, kvbuf, btable, obuf);

    // 4. proj = o @ proj_w^T + proj_b
    gemm_kernel<1><<<dim3(T_TOK / 64, C_DIM / 64), 256, 0, stream>>>(
        obuf, proj_w, proj_b, nullptr, nullptr, pbuf, T_TOK, C_DIM, C_DIM);

    // 5. window reverse + residual + ls1 -> d_out  (this is x1)
    reverse_residual_kernel<<<(T_TOK * 96 + 255) / 256, 256, 0, stream>>>(
        x, pbuf, ls1, out);

    // 6. LN2  (d_out -> h)
    ln_kernel<false><<<(T_TOK * 64 + 255) / 256, 256, 0, stream>>>(out, n2g, n2b, hbuf);

    // 7. hidden = gelu(h @ fc1_w^T + fc1_b)
    gemm_kernel<2><<<dim3(T_TOK / 64, 4 * C_DIM / 64), 256, 0, stream>>>(
        hbuf, fc1_w, fc1_b, nullptr, nullptr, hidden, T_TOK, 4 * C_DIM, C_DIM);

    // 8. out = x1 + ls2 * (hidden @ fc2_w^T + fc2_b)   (reads res from d_out)
    gemm_kernel<3><<<dim3(T_TOK / 64, C_DIM / 64), 256, 0, stream>>>(
        hidden, fc2_w, fc2_b, out, ls2, out, T_TOK, C_DIM, 4 * C_DIM);
}

// Round 2
// 535.424 us; speedup vs baseline: 3.8748x; 3.8748x over previous
//
#include <hip/hip_runtime.h>
#include <hip/hip_bf16.h>
#include <math.h>

// Swin block: B=8, H=W=56, C=384, ws=7, nh=12
#define T_TOK 25088   // B * L
#define L_DIM 3136
#define C_DIM 384
#define NHEADS 12
#define HDIM 32
#define NWIN 512
#define NTOK 49

typedef __attribute__((ext_vector_type(8))) short bf16x8_t;   // MFMA A/B frag (4 VGPRs)
typedef __attribute__((ext_vector_type(4))) float f32x4;      // MFMA C/D frag

__device__ __forceinline__ float gelu_exact(float x) {
    return 0.5f * x * (1.0f + erff(x * 0.70710678118654752440f));
}
__device__ __forceinline__ float bf2f(unsigned short u) {
    return __uint_as_float(((unsigned)u) << 16);
}
__device__ __forceinline__ unsigned short f2bf(float f) {
    __hip_bfloat16 h = __float2bfloat16(f);   // RNE
    return *(unsigned short*)&h;
}

// async global->LDS, 16B per lane; LDS dest must be wave-uniform base + lane*16
__device__ __forceinline__ void gload_lds16(const unsigned short* g, unsigned short* l) {
    __builtin_amdgcn_global_load_lds(
        (const __attribute__((address_space(1))) unsigned int*)(const void*)g,
        (__attribute__((address_space(3))) unsigned int*)(void*)l,
        16, 0, 0);
}

// ---------------------------------------------------------------------------
// Fused fp32 -> bf16 weight conversion. dst = [qkv(442368 f4) | proj | fc1 | fc2]
// i indexes float4 chunks; segments contiguous in dst in the same order.
// ---------------------------------------------------------------------------
__global__ __launch_bounds__(256) void convert_weights_kernel(
    const float* __restrict__ qw, const float* __restrict__ kvw,
    const float* __restrict__ pw, const float* __restrict__ f1,
    const float* __restrict__ f2, unsigned short* __restrict__ dst)
{
    int i = blockIdx.x * 256 + threadIdx.x;   // total 442368 float4s
    if (i >= 442368) return;
    const float* src; int off;
    if      (i < 36864)  { src = qw;  off = i;          }
    else if (i < 110592) { src = kvw; off = i - 36864;  }
    else if (i < 147456) { src = pw;  off = i - 110592; }
    else if (i < 294912) { src = f1;  off = i - 147456; }
    else                 { src = f2;  off = i - 294912; }
    float4 v = ((const float4*)src)[off];
    unsigned short* d = dst + (size_t)i * 4;
    d[0] = f2bf(v.x); d[1] = f2bf(v.y); d[2] = f2bf(v.z); d[3] = f2bf(v.w);
}

// ---------------------------------------------------------------------------
// LayerNorm, one wave per token row of 384. WINDOWED scatters to window layout.
// OUTB: write bf16 (ushort) else fp32.
// ---------------------------------------------------------------------------
template<bool WINDOWED, bool OUTB>
__global__ __launch_bounds__(256) void ln_kernel(
    const float* __restrict__ x, const float* __restrict__ g,
    const float* __restrict__ b, void* __restrict__ yv)
{
    int gid  = blockIdx.x * 256 + threadIdx.x;
    int t    = gid >> 6;
    int lane = threadIdx.x & 63;
    if (t >= T_TOK) return;

    const float* row = x + (size_t)t * C_DIM;
    float vals[6];
    float s = 0.f, s2 = 0.f;
#pragma unroll
    for (int i = 0; i < 6; ++i) {
        float v = row[lane + i * 64];
        vals[i] = v; s += v; s2 += v * v;
    }
#pragma unroll
    for (int off = 32; off; off >>= 1) {
        s  += __shfl_down(s, off);
        s2 += __shfl_down(s2, off);
    }
    s  = __shfl(s, 0);
    s2 = __shfl(s2, 0);
    float mean = s * (1.0f / C_DIM);
    float var  = s2 * (1.0f / C_DIM) - mean * mean;
    float rstd = rsqrtf(var + 1e-5f);

    size_t orow;
    if (WINDOWED) {
        int bb = t / L_DIM, l = t % L_DIM;
        int hr = l / 56, wc = l % 56;
        int w  = (bb * 8 + hr / 7) * 8 + wc / 7;
        int n  = (hr % 7) * 7 + (wc % 7);
        orow = ((size_t)w * NTOK + n) * C_DIM;
    } else {
        orow = (size_t)t * C_DIM;
    }
#pragma unroll
    for (int i = 0; i < 6; ++i) {
        int c = lane + i * 64;
        float o = (vals[i] - mean) * rstd * g[c] + b[c];
        if (OUTB) ((unsigned short*)yv)[orow + c] = f2bf(o);
        else      ((float*)yv)[orow + c] = o;
    }
}

// ---------------------------------------------------------------------------
// bf16 MFMA GEMM: Y[M x Nn] = X[M x K] @ W[Nn x K]^T  (torch Linear layout)
// 128x128 tile, BK=32, 256 thr = 4 waves (2x2), each wave 64x64 = 4x4 frags
// of mfma_f32_16x16x32_bf16. global_load_lds 16B staging (linear LDS).
// EPI: 0=none 1=+bias 2=gelu(y+bias) 3=res + ls*(y+bias).  OUTB: bf16 out.
// M%128==0, Nn%128==0, K%32==0 (holds for all uses here).
// ---------------------------------------------------------------------------
template<int EPI, bool OUTB>
__global__ __launch_bounds__(256) void gemm_bf16_kernel(
    const unsigned short* __restrict__ X, const unsigned short* __restrict__ W,
    const float* __restrict__ bias, const float* __restrict__ res,
    const float* __restrict__ ls, void* __restrict__ Yv,
    int M, int Nn, int K)
{
    __shared__ unsigned short As[128 * 32];   // 8 KB
    __shared__ unsigned short Bs[128 * 32];   // 8 KB

    int tid  = threadIdx.x;
    int m0   = blockIdx.x * 128, n0 = blockIdx.y * 128;
    int wave = tid >> 6, lane = tid & 63;
    int wr   = wave >> 1, wc = wave & 1;      // wave tile origin /64
    int lrow = lane & 15;
    int lk   = (lane >> 4) << 3;              // k offset of this lane's 8 elems

    // staging: lane covers row tid/4 (+64 second round), cols (tid%4)*8..+8
    int srow = tid >> 2;
    int scol = (tid & 3) << 3;

    f32x4 acc[4][4] = {};

    for (int k0 = 0; k0 < K; k0 += 32) {
        gload_lds16(X + (size_t)(m0 + srow) * K + k0 + scol,      As + tid * 8);
        gload_lds16(X + (size_t)(m0 + 64 + srow) * K + k0 + scol, As + 2048 + tid * 8);
        gload_lds16(W + (size_t)(n0 + srow) * K + k0 + scol,      Bs + tid * 8);
        gload_lds16(W + (size_t)(n0 + 64 + srow) * K + k0 + scol, Bs + 2048 + tid * 8);
        __syncthreads();   // compiler emits vmcnt(0) drain before barrier

        bf16x8_t av[4], bv[4];
#pragma unroll
        for (int i = 0; i < 4; ++i)
            av[i] = *(const bf16x8_t*)&As[(wr * 64 + i * 16 + lrow) * 32 + lk];
#pragma unroll
        for (int j = 0; j < 4; ++j)
            bv[j] = *(const bf16x8_t*)&Bs[(wc * 64 + j * 16 + lrow) * 32 + lk];
#pragma unroll
        for (int i = 0; i < 4; ++i)
#pragma unroll
            for (int j = 0; j < 4; ++j)
                acc[i][j] = __builtin_amdgcn_mfma_f32_16x16x32_bf16(
                    av[i], bv[j], acc[i][j], 0, 0, 0);
        __syncthreads();
    }

    // epilogue: C[row=(lane>>4)*4+q][col=lane&15] per frag (m89-verified layout)
    int colbase = n0 + wc * 64 + lrow;
    int rowbase = m0 + wr * 64 + ((lane >> 4) << 2);
#pragma unroll
    for (int j = 0; j < 4; ++j) {
        int col = colbase + j * 16;
        float bb = (EPI >= 1) ? bias[col] : 0.f;
        float lv = (EPI == 3) ? ls[col] : 0.f;
#pragma unroll
        for (int i = 0; i < 4; ++i) {
#pragma unroll
            for (int q = 0; q < 4; ++q) {
                int row = rowbase + i * 16 + q;
                float v = acc[i][j][q];
                if (EPI >= 1) v += bb;
                if (EPI == 2) v = gelu_exact(v);
                if (EPI == 3) v = res[(size_t)row * Nn + col] + lv * v;
                if (OUTB) ((unsigned short*)Yv)[(size_t)row * Nn + col] = f2bf(v);
                else      ((float*)Yv)[(size_t)row * Nn + col] = v;
            }
        }
    }
}

// ---------------------------------------------------------------------------
// Windowed attention: one block per (window, head). N=49, hd=32.
// qkv bf16 (Bw*49, 1152): q at h*32, k at 384+h*32, v at 768+h*32.
// fp32 math, bf16 output (window layout, stride 384).
// ---------------------------------------------------------------------------
__global__ __launch_bounds__(256) void attn_kernel(
    const unsigned short* __restrict__ qkv,
    const float* __restrict__ bias_table, unsigned short* __restrict__ o)
{
    __shared__ float qs[NTOK][33];
    __shared__ float ks[NTOK][33];
    __shared__ float vs[NTOK][33];
    __shared__ float ss[NTOK][50];

    int w = blockIdx.x / NHEADS;
    int h = blockIdx.x % NHEADS;
    int tid = threadIdx.x;

    for (int e = tid; e < NTOK * 32; e += 256) {
        int n = e >> 5, d = e & 31;
        size_t base = ((size_t)w * NTOK + n) * 1152 + h * HDIM + d;
        qs[n][d] = bf2f(qkv[base]);
        ks[n][d] = bf2f(qkv[base + 384]);
        vs[n][d] = bf2f(qkv[base + 768]);
    }
    __syncthreads();

    const float scale = 0.17677669529663687f;  // 1/sqrt(32)
    for (int e = tid; e < NTOK * NTOK; e += 256) {
        int n = e / NTOK, m = e % NTOK;
        float acc = 0.f;
#pragma unroll
        for (int kk = 0; kk < 32; ++kk) acc += qs[n][kk] * ks[m][kk];
        int i1 = n / 7, j1 = n % 7, i2 = m / 7, j2 = m % 7;
        int idx = (i1 - i2 + 6) * 13 + (j1 - j2 + 6);
        ss[n][m] = acc * scale + bias_table[idx * NHEADS + h];
    }
    __syncthreads();

    int wv = tid >> 6, lane = tid & 63;
    for (int r = wv; r < NTOK; r += 4) {
        float v = (lane < NTOK) ? ss[r][lane] : -INFINITY;
        float mx = v;
#pragma unroll
        for (int off = 32; off; off >>= 1) mx = fmaxf(mx, __shfl_down(mx, off));
        mx = __shfl(mx, 0);
        float ev = (lane < NTOK) ? expf(v - mx) : 0.f;
        float sum = ev;
#pragma unroll
        for (int off = 32; off; off >>= 1) sum += __shfl_down(sum, off);
        sum = __shfl(sum, 0);
        if (lane < NTOK) ss[r][lane] = ev / sum;
    }
    __syncthreads();

    for (int e = tid; e < NTOK * 32; e += 256) {
        int n = e >> 5, d = e & 31;
        float acc = 0.f;
#pragma unroll
        for (int m = 0; m < NTOK; ++m) acc += ss[n][m] * vs[m][d];
        o[((size_t)w * NTOK + n) * C_DIM + h * HDIM + d] = f2bf(acc);
    }
}

// ---------------------------------------------------------------------------
// Window reverse + residual + layer-scale (fp32): out = x + ls1 * p(window)
// ---------------------------------------------------------------------------
__global__ __launch_bounds__(256) void reverse_residual_kernel(
    const float* __restrict__ x, const float* __restrict__ p,
    const float* __restrict__ ls1, float* __restrict__ out)
{
    int idx = blockIdx.x * 256 + threadIdx.x;  // over T_TOK * 96
    int t = idx / 96;
    int c = (idx % 96) * 4;
    if (t >= T_TOK) return;
    int bb = t / L_DIM, l = t % L_DIM;
    int hr = l / 56, wc = l % 56;
    int w = (bb * 8 + hr / 7) * 8 + wc / 7;
    int n = (hr % 7) * 7 + (wc % 7);
    float4 pv = *(const float4*)(p + ((size_t)w * NTOK + n) * C_DIM + c);
    float4 xv = *(const float4*)(x + (size_t)t * C_DIM + c);
    float4 lv = *(const float4*)(ls1 + c);
    float4 ov;
    ov.x = xv.x + lv.x * pv.x;
    ov.y = xv.y + lv.y * pv.y;
    ov.z = xv.z + lv.z * pv.z;
    ov.w = xv.w + lv.w * pv.w;
    *(float4*)(out + (size_t)t * C_DIM + c) = ov;
}

// ---------------------------------------------------------------------------
extern "C" void kernel_launch(void* const* d_in, const int* in_sizes, int n_in,
                              void* d_out, int out_size, void* d_ws, size_t ws_size,
                              hipStream_t stream)
{
    const float* x       = (const float*)d_in[0];
    const float* q_w     = (const float*)d_in[1];
    const float* kv_w    = (const float*)d_in[2];
    const float* proj_w  = (const float*)d_in[3];
    const float* proj_b  = (const float*)d_in[4];
    const float* fc1_w   = (const float*)d_in[5];
    const float* fc1_b   = (const float*)d_in[6];
    const float* fc2_w   = (const float*)d_in[7];
    const float* fc2_b   = (const float*)d_in[8];
    const float* n1g     = (const float*)d_in[9];
    const float* n1b     = (const float*)d_in[10];
    const float* n2g     = (const float*)d_in[11];
    const float* n2b     = (const float*)d_in[12];
    const float* ls1     = (const float*)d_in[13];
    const float* ls2     = (const float*)d_in[14];
    const float* btable  = (const float*)d_in[15];

    float* out = (float*)d_out;
    char*  ws  = (char*)d_ws;

    // Workspace layout (157.7 MB total; harness provides >= 192 MB proven in R0):
    //   A @ 0         : qkv bf16 (57.8 MB) -> hidden bf16 (77 MB)
    //   B @ 77070336  : pbuf fp32 (38.5 MB)
    //   C @ 115605504 : xw bf16 (19.3 MB) -> obuf bf16
    //   D @ 134873088 : hbuf bf16 (19.3 MB)
    //   E @ 154140672 : weights bf16 (3.54 MB)
    unsigned short* qkvbuf = (unsigned short*)(ws);
    unsigned short* hidden = (unsigned short*)(ws);
    float*          pbuf   = (float*)(ws + 77070336);
    unsigned short* xw     = (unsigned short*)(ws + 115605504);
    unsigned short* obuf   = xw;
    unsigned short* hbuf   = (unsigned short*)(ws + 134873088);
    unsigned short* wqkv   = (unsigned short*)(ws + 154140672);
    unsigned short* wproj  = wqkv + 442368;
    unsigned short* wfc1   = wproj + 147456;
    unsigned short* wfc2   = wfc1 + 589824;

    // 0. weights -> bf16 (single fused kernel)
    convert_weights_kernel<<<1728, 256, 0, stream>>>(q_w, kv_w, proj_w, fc1_w, fc2_w, wqkv);

    // 1. LN1 + window partition -> xw (bf16)
    ln_kernel<true, true><<<(T_TOK * 64 + 255) / 256, 256, 0, stream>>>(x, n1g, n1b, xw);

    // 2. fused qkv = xw @ [q_w;kv_w]^T  -> bf16 (M=25088, N=1152, K=384)
    gemm_bf16_kernel<0, true><<<dim3(T_TOK / 128, 1152 / 128), 256, 0, stream>>>(
        xw, wqkv, nullptr, nullptr, nullptr, qkvbuf, T_TOK, 1152, C_DIM);

    // 3. windowed attention -> obuf (bf16, overwrites xw)
    attn_kernel<<<NWIN * NHEADS, 256, 0, stream>>>(qkvbuf, btable, obuf);

    // 4. proj = obuf @ proj_w^T + proj_b -> pbuf (fp32)
    gemm_bf16_kernel<1, false><<<dim3(T_TOK / 128, C_DIM / 128), 256, 0, stream>>>(
        obuf, wproj, proj_b, nullptr, nullptr, pbuf, T_TOK, C_DIM, C_DIM);

    // 5. window reverse + residual + ls1 -> d_out (= x1, fp32)
    reverse_residual_kernel<<<(T_TOK * 96 + 255) / 256, 256, 0, stream>>>(
        x, pbuf, ls1, out);

    // 6. LN2 -> hbuf (bf16)
    ln_kernel<false, true><<<(T_TOK * 64 + 255) / 256, 256, 0, stream>>>(out, n2g, n2b, hbuf);

    // 7. hidden = gelu(hbuf @ fc1_w^T + fc1_b) -> bf16 (N=1536; overwrites qkv)
    gemm_bf16_kernel<2, true><<<dim3(T_TOK / 128, 1536 / 128), 256, 0, stream>>>(
        hbuf, wfc1, fc1_b, nullptr, nullptr, hidden, T_TOK, 1536, C_DIM);

    // 8. d_out = x1 + ls2 * (hidden @ fc2_w^T + fc2_b)  (K=1536)
    gemm_bf16_kernel<3, false><<<dim3(T_TOK / 128, C_DIM / 128), 256, 0, stream>>>(
        hidden, wfc2, fc2_b, out, ls2, out, T_TOK, C_DIM, 1536);
}

// Round 4
// 426.115 us; speedup vs baseline: 4.8688x; 1.2565x over previous
//
#include <hip/hip_runtime.h>
#include <hip/hip_bf16.h>
#include <math.h>

// Swin block: B=8, H=W=56, C=384, ws=7, nh=12
#define T_TOK 25088   // B * L
#define L_DIM 3136
#define C_DIM 384
#define NHEADS 12
#define HDIM 32
#define NWIN 512
#define NTOK 49

typedef __attribute__((ext_vector_type(8))) short bf16x8_t;   // MFMA A/B frag (4 VGPRs)
typedef __attribute__((ext_vector_type(4))) float f32x4;      // MFMA C/D frag

__device__ __forceinline__ float gelu_exact(float x) {
    return 0.5f * x * (1.0f + erff(x * 0.70710678118654752440f));
}
__device__ __forceinline__ float bf2f(unsigned short u) {
    return __uint_as_float(((unsigned)u) << 16);
}
__device__ __forceinline__ unsigned short f2bf(float f) {
    __hip_bfloat16 h = __float2bfloat16(f);   // RNE
    return *(unsigned short*)&h;
}

// async global->LDS, 16B per lane; LDS dest must be wave-uniform base + lane*16
__device__ __forceinline__ void gload_lds16(const unsigned short* g, unsigned short* l) {
    __builtin_amdgcn_global_load_lds(
        (const __attribute__((address_space(1))) unsigned int*)(const void*)g,
        (__attribute__((address_space(3))) unsigned int*)(void*)l,
        16, 0, 0);
}

// ---------------------------------------------------------------------------
// Fused fp32 -> bf16 weight conversion. dst = [qkv(442368 f4) | proj | fc1 | fc2]
// ---------------------------------------------------------------------------
__global__ __launch_bounds__(256) void convert_weights_kernel(
    const float* __restrict__ qw, const float* __restrict__ kvw,
    const float* __restrict__ pw, const float* __restrict__ f1,
    const float* __restrict__ f2, unsigned short* __restrict__ dst)
{
    int i = blockIdx.x * 256 + threadIdx.x;   // total 442368 float4s
    if (i >= 442368) return;
    const float* src; int off;
    if      (i < 36864)  { src = qw;  off = i;          }
    else if (i < 110592) { src = kvw; off = i - 36864;  }
    else if (i < 147456) { src = pw;  off = i - 110592; }
    else if (i < 294912) { src = f1;  off = i - 147456; }
    else                 { src = f2;  off = i - 294912; }
    float4 v = ((const float4*)src)[off];
    unsigned short* d = dst + (size_t)i * 4;
    d[0] = f2bf(v.x); d[1] = f2bf(v.y); d[2] = f2bf(v.z); d[3] = f2bf(v.w);
}

// ---------------------------------------------------------------------------
// Pre-expand relative-position bias: biasmat[h][n][m], 12*49*49 floats.
// ---------------------------------------------------------------------------
__global__ __launch_bounds__(256) void bias_precompute_kernel(
    const float* __restrict__ table, float* __restrict__ biasmat)
{
    int e = blockIdx.x * 256 + threadIdx.x;   // 28812 total
    if (e >= 28812) return;
    int h = e / 2401, r = e % 2401;
    int n = r / 49, m = r % 49;
    int i1 = n / 7, j1 = n % 7, i2 = m / 7, j2 = m % 7;
    int idx = (i1 - i2 + 6) * 13 + (j1 - j2 + 6);
    biasmat[e] = table[idx * NHEADS + h];
}

// ---------------------------------------------------------------------------
// LayerNorm, one wave per token row of 384. WINDOWED scatters to window layout.
// ---------------------------------------------------------------------------
template<bool WINDOWED, bool OUTB>
__global__ __launch_bounds__(256) void ln_kernel(
    const float* __restrict__ x, const float* __restrict__ g,
    const float* __restrict__ b, void* __restrict__ yv)
{
    int gid  = blockIdx.x * 256 + threadIdx.x;
    int t    = gid >> 6;
    int lane = threadIdx.x & 63;
    if (t >= T_TOK) return;

    const float* row = x + (size_t)t * C_DIM;
    float vals[6];
    float s = 0.f, s2 = 0.f;
#pragma unroll
    for (int i = 0; i < 6; ++i) {
        float v = row[lane + i * 64];
        vals[i] = v; s += v; s2 += v * v;
    }
#pragma unroll
    for (int off = 32; off; off >>= 1) {
        s  += __shfl_down(s, off);
        s2 += __shfl_down(s2, off);
    }
    s  = __shfl(s, 0);
    s2 = __shfl(s2, 0);
    float mean = s * (1.0f / C_DIM);
    float var  = s2 * (1.0f / C_DIM) - mean * mean;
    float rstd = rsqrtf(var + 1e-5f);

    size_t orow;
    if (WINDOWED) {
        int bb = t / L_DIM, l = t % L_DIM;
        int hr = l / 56, wc = l % 56;
        int w  = (bb * 8 + hr / 7) * 8 + wc / 7;
        int n  = (hr % 7) * 7 + (wc % 7);
        orow = ((size_t)w * NTOK + n) * C_DIM;
    } else {
        orow = (size_t)t * C_DIM;
    }
#pragma unroll
    for (int i = 0; i < 6; ++i) {
        int c = lane + i * 64;
        float o = (vals[i] - mean) * rstd * g[c] + b[c];
        if (OUTB) ((unsigned short*)yv)[orow + c] = f2bf(o);
        else      ((float*)yv)[orow + c] = o;
    }
}

// ---------------------------------------------------------------------------
// bf16 MFMA GEMM: Y[M x Nn] = X[M x K] @ W[Nn x K]^T, 128x128 tile, BK=32,
// 4 waves, global_load_lds staging. Bijective XCD swizzle on the tile id.
// EPI: 0=none 1=+bias 2=gelu(y+bias) 3=res + ls*(y+bias).  OUTB: bf16 out.
// ---------------------------------------------------------------------------
template<int EPI, bool OUTB>
__global__ __launch_bounds__(256) void gemm_bf16_kernel(
    const unsigned short* __restrict__ X, const unsigned short* __restrict__ W,
    const float* __restrict__ bias, const float* __restrict__ res,
    const float* __restrict__ ls, void* __restrict__ Yv,
    int M, int Nn, int K)
{
    __shared__ unsigned short As[128 * 32];   // 8 KB
    __shared__ unsigned short Bs[128 * 32];   // 8 KB

    // XCD-aware bijective swizzle (m204): consecutive swz ids share the A panel.
    int Nt  = gridDim.y;
    int nwg = gridDim.x * Nt;
    int id  = blockIdx.y * gridDim.x + blockIdx.x;   // hw dispatch order, x fastest
    int qq  = nwg >> 3, rr = nwg & 7;
    int xcd = id & 7, pos = id >> 3;
    int swz = (xcd < rr) ? (xcd * (qq + 1) + pos)
                         : (rr * (qq + 1) + (xcd - rr) * qq + pos);
    int m0 = (swz / Nt) * 128, n0 = (swz % Nt) * 128;

    int tid  = threadIdx.x;
    int wave = tid >> 6, lane = tid & 63;
    int wr   = wave >> 1, wc = wave & 1;
    int lrow = lane & 15;
    int lk   = (lane >> 4) << 3;

    int srow = tid >> 2;
    int scol = (tid & 3) << 3;

    f32x4 acc[4][4] = {};

    for (int k0 = 0; k0 < K; k0 += 32) {
        gload_lds16(X + (size_t)(m0 + srow) * K + k0 + scol,      As + tid * 8);
        gload_lds16(X + (size_t)(m0 + 64 + srow) * K + k0 + scol, As + 2048 + tid * 8);
        gload_lds16(W + (size_t)(n0 + srow) * K + k0 + scol,      Bs + tid * 8);
        gload_lds16(W + (size_t)(n0 + 64 + srow) * K + k0 + scol, Bs + 2048 + tid * 8);
        __syncthreads();

        bf16x8_t av[4], bv[4];
#pragma unroll
        for (int i = 0; i < 4; ++i)
            av[i] = *(const bf16x8_t*)&As[(wr * 64 + i * 16 + lrow) * 32 + lk];
#pragma unroll
        for (int j = 0; j < 4; ++j)
            bv[j] = *(const bf16x8_t*)&Bs[(wc * 64 + j * 16 + lrow) * 32 + lk];
#pragma unroll
        for (int i = 0; i < 4; ++i)
#pragma unroll
            for (int j = 0; j < 4; ++j)
                acc[i][j] = __builtin_amdgcn_mfma_f32_16x16x32_bf16(
                    av[i], bv[j], acc[i][j], 0, 0, 0);
        __syncthreads();
    }

    int colbase = n0 + wc * 64 + lrow;
    int rowbase = m0 + wr * 64 + ((lane >> 4) << 2);
#pragma unroll
    for (int j = 0; j < 4; ++j) {
        int col = colbase + j * 16;
        float bb = (EPI >= 1) ? bias[col] : 0.f;
        float lv = (EPI == 3) ? ls[col] : 0.f;
#pragma unroll
        for (int i = 0; i < 4; ++i) {
#pragma unroll
            for (int q = 0; q < 4; ++q) {
                int row = rowbase + i * 16 + q;
                float v = acc[i][j][q];
                if (EPI >= 1) v += bb;
                if (EPI == 2) v = gelu_exact(v);
                if (EPI == 3) v = res[(size_t)row * Nn + col] + lv * v;
                if (OUTB) ((unsigned short*)Yv)[(size_t)row * Nn + col] = f2bf(v);
                else      ((float*)Yv)[(size_t)row * Nn + col] = v;
            }
        }
    }
}

// ---------------------------------------------------------------------------
// MFMA windowed attention: ONE WAVE per (window, head). N=49 padded to 64,
// hd=32 = one K-step of mfma_f32_16x16x32_bf16.
//   S = Q K^T : Q/K frags read straight from global (row-major 16B chunks).
//   softmax in registers (C layout: row=q-token, col=k-token).
//   P -> LDS with XOR swizzle (row-major [64][128B] would be 32-way conflict).
//   O = P V : P A-frags from LDS, V B-frags column-gathered from stride-40 LDS.
// NaN hygiene (R3 fail): V pad rows 49..63 ZEROED (stale LDS could be NaN and
// 0*NaN=NaN in the PV MFMA); pad-ROW bias = 0 not -inf (all -inf row gives
// expf(-inf - -inf) = NaN). Pad COLUMNS keep -inf / e=0 for exact softmax.
// ---------------------------------------------------------------------------
__global__ __launch_bounds__(64) void attn_mfma_kernel(
    const unsigned short* __restrict__ qkv,
    const float* __restrict__ biasmat,   // [12][49][49]
    unsigned short* __restrict__ o)
{
    __shared__ unsigned short vs[64 * 40];   // V rows, stride 40 (bank stagger)
    __shared__ unsigned short ps[64 * 64];   // P, XOR-swizzled rows of 128B

    int w    = blockIdx.x / NHEADS;
    int h    = blockIdx.x % NHEADS;
    int lane = threadIdx.x;
    int g    = lane >> 4;       // k-chunk group (frag k-offset = g*8)
    int lr   = lane & 15;

    // ---- stage V (rows 0..48) into LDS, 16B per task ----
    for (int t = lane; t < 196; t += 64) {
        int row = t >> 2, c = t & 3;
        bf16x8_t v = *(const bf16x8_t*)(qkv + ((size_t)w * NTOK + row) * 1152 + 768 + h * HDIM + c * 8);
        *(bf16x8_t*)(vs + row * 40 + c * 8) = v;
    }
    // ---- zero V pad rows 49..63 (15 rows x 4 chunks = 60 tasks) ----
    if (lane < 60) {
        int row = 49 + (lane >> 2), c = lane & 3;
        bf16x8_t z = {};
        *(bf16x8_t*)(vs + row * 40 + c * 8) = z;
    }

    // ---- Q, K fragments direct from global (clamp padded rows) ----
    bf16x8_t qf[4], kf[4];
#pragma unroll
    for (int i = 0; i < 4; ++i) {
        int qrow = i * 16 + lr; if (qrow > 48) qrow = 0;
        qf[i] = *(const bf16x8_t*)(qkv + ((size_t)w * NTOK + qrow) * 1152 + h * HDIM + g * 8);
        kf[i] = *(const bf16x8_t*)(qkv + ((size_t)w * NTOK + qrow) * 1152 + 384 + h * HDIM + g * 8);
    }

    // ---- S = Q K^T  (16 MFMAs, single K-step) ----
    f32x4 sacc[4][4];
    const f32x4 zf = {0.f, 0.f, 0.f, 0.f};
#pragma unroll
    for (int i = 0; i < 4; ++i)
#pragma unroll
        for (int j = 0; j < 4; ++j)
            sacc[i][j] = __builtin_amdgcn_mfma_f32_16x16x32_bf16(qf[i], kf[j], zf, 0, 0, 0);

    // ---- softmax over k (cols), rows are (ni, g, q), cols are (lr, mj) ----
    const float scale = 0.17677669529663687f;  // 1/sqrt(32)
    const float* bh = biasmat + h * 2401;
#pragma unroll
    for (int ni = 0; ni < 4; ++ni) {
#pragma unroll
        for (int q = 0; q < 4; ++q) {
            int row = ni * 16 + g * 4 + q;
            float sv[4];
#pragma unroll
            for (int mj = 0; mj < 4; ++mj) {
                int col = lr + mj * 16;
                // pad cols -> -inf (excluded); pad rows -> 0 bias (finite,
                // harmless: their outputs are never stored)
                float bias = (col < NTOK)
                    ? ((row < NTOK) ? bh[row * NTOK + col] : 0.f)
                    : -INFINITY;
                sv[mj] = sacc[ni][mj][q] * scale + bias;
            }
            float mx = fmaxf(fmaxf(sv[0], sv[1]), fmaxf(sv[2], sv[3]));
#pragma unroll
            for (int d = 1; d < 16; d <<= 1) mx = fmaxf(mx, __shfl_xor(mx, d));
            float e[4], sum = 0.f;
#pragma unroll
            for (int mj = 0; mj < 4; ++mj) {
                int col = lr + mj * 16;
                e[mj] = (col < NTOK) ? expf(sv[mj] - mx) : 0.f;
                sum += e[mj];
            }
#pragma unroll
            for (int d = 1; d < 16; d <<= 1) sum += __shfl_xor(sum, d);
            float rinv = 1.f / sum;
#pragma unroll
            for (int mj = 0; mj < 4; ++mj) {
                int col = lr + mj * 16;
                int byteoff = (row * 128 + col * 2) ^ ((row & 7) << 4);
                *(unsigned short*)((char*)ps + byteoff) = f2bf(e[mj] * rinv);
            }
        }
    }
    __syncthreads();

    // ---- O = P V  (2 k-steps x 4 row-tiles x 2 d-tiles) ----
    f32x4 oacc[4][2] = {};
#pragma unroll
    for (int ks = 0; ks < 2; ++ks) {
        bf16x8_t pf[4];
#pragma unroll
        for (int ni = 0; ni < 4; ++ni) {
            int row = ni * 16 + lr;
            int byteoff = (row * 128 + (ks * 32 + g * 8) * 2) ^ ((row & 7) << 4);
            pf[ni] = *(const bf16x8_t*)((char*)ps + byteoff);
        }
        bf16x8_t vf[2];
#pragma unroll
        for (int dj = 0; dj < 2; ++dj) {
#pragma unroll
            for (int j = 0; j < 8; ++j)
                vf[dj][j] = (short)vs[(ks * 32 + g * 8 + j) * 40 + lr + dj * 16];
        }
#pragma unroll
        for (int ni = 0; ni < 4; ++ni)
#pragma unroll
            for (int dj = 0; dj < 2; ++dj)
                oacc[ni][dj] = __builtin_amdgcn_mfma_f32_16x16x32_bf16(
                    pf[ni], vf[dj], oacc[ni][dj], 0, 0, 0);
    }

    // ---- store O (rows < 49) ----
#pragma unroll
    for (int ni = 0; ni < 4; ++ni) {
#pragma unroll
        for (int q = 0; q < 4; ++q) {
            int row = ni * 16 + g * 4 + q;
            if (row < NTOK) {
#pragma unroll
                for (int dj = 0; dj < 2; ++dj)
                    o[((size_t)w * NTOK + row) * C_DIM + h * HDIM + lr + dj * 16] =
                        f2bf(oacc[ni][dj][q]);
            }
        }
    }
}

// ---------------------------------------------------------------------------
// Window reverse + residual + layer-scale (fp32): out = x + ls1 * p(window)
// ---------------------------------------------------------------------------
__global__ __launch_bounds__(256) void reverse_residual_kernel(
    const float* __restrict__ x, const float* __restrict__ p,
    const float* __restrict__ ls1, float* __restrict__ out)
{
    int idx = blockIdx.x * 256 + threadIdx.x;  // over T_TOK * 96
    int t = idx / 96;
    int c = (idx % 96) * 4;
    if (t >= T_TOK) return;
    int bb = t / L_DIM, l = t % L_DIM;
    int hr = l / 56, wc = l % 56;
    int w = (bb * 8 + hr / 7) * 8 + wc / 7;
    int n = (hr % 7) * 7 + (wc % 7);
    float4 pv = *(const float4*)(p + ((size_t)w * NTOK + n) * C_DIM + c);
    float4 xv = *(const float4*)(x + (size_t)t * C_DIM + c);
    float4 lv = *(const float4*)(ls1 + c);
    float4 ov;
    ov.x = xv.x + lv.x * pv.x;
    ov.y = xv.y + lv.y * pv.y;
    ov.z = xv.z + lv.z * pv.z;
    ov.w = xv.w + lv.w * pv.w;
    *(float4*)(out + (size_t)t * C_DIM + c) = ov;
}

// ---------------------------------------------------------------------------
extern "C" void kernel_launch(void* const* d_in, const int* in_sizes, int n_in,
                              void* d_out, int out_size, void* d_ws, size_t ws_size,
                              hipStream_t stream)
{
    const float* x       = (const float*)d_in[0];
    const float* q_w     = (const float*)d_in[1];
    const float* kv_w    = (const float*)d_in[2];
    const float* proj_w  = (const float*)d_in[3];
    const float* proj_b  = (const float*)d_in[4];
    const float* fc1_w   = (const float*)d_in[5];
    const float* fc1_b   = (const float*)d_in[6];
    const float* fc2_w   = (const float*)d_in[7];
    const float* fc2_b   = (const float*)d_in[8];
    const float* n1g     = (const float*)d_in[9];
    const float* n1b     = (const float*)d_in[10];
    const float* n2g     = (const float*)d_in[11];
    const float* n2b     = (const float*)d_in[12];
    const float* ls1     = (const float*)d_in[13];
    const float* ls2     = (const float*)d_in[14];
    const float* btable  = (const float*)d_in[15];

    float* out = (float*)d_out;
    char*  ws  = (char*)d_ws;

    // Workspace layout (161.4 MB; >=192 MB proven available in R0):
    //   0          qkv bf16 (57.8 MB) -> hidden bf16 (77 MB)
    //   77070336   pbuf fp32 (38.5 MB)
    //   115605504  xw bf16 (19.3 MB) -> obuf bf16
    //   134873088  hbuf bf16 (19.3 MB)
    //   154140672  weights bf16 (7.08 MB)
    //   161218560  biasmat fp32 (115 KB)
    unsigned short* qkvbuf = (unsigned short*)(ws);
    unsigned short* hidden = (unsigned short*)(ws);
    float*          pbuf   = (float*)(ws + 77070336);
    unsigned short* xw     = (unsigned short*)(ws + 115605504);
    unsigned short* obuf   = xw;
    unsigned short* hbuf   = (unsigned short*)(ws + 134873088);
    unsigned short* wqkv   = (unsigned short*)(ws + 154140672);
    unsigned short* wproj  = wqkv + 442368;
    unsigned short* wfc1   = wproj + 147456;
    unsigned short* wfc2   = wfc1 + 589824;
    float*          biasmat= (float*)(ws + 161218560);

    // 0. weights -> bf16 ; relative-position bias matrix
    convert_weights_kernel<<<1728, 256, 0, stream>>>(q_w, kv_w, proj_w, fc1_w, fc2_w, wqkv);
    bias_precompute_kernel<<<113, 256, 0, stream>>>(btable, biasmat);

    // 1. LN1 + window partition -> xw (bf16)
    ln_kernel<true, true><<<(T_TOK * 64 + 255) / 256, 256, 0, stream>>>(x, n1g, n1b, xw);

    // 2. fused qkv = xw @ [q_w;kv_w]^T  (M=25088, N=1152, K=384)
    gemm_bf16_kernel<0, true><<<dim3(T_TOK / 128, 1152 / 128), 256, 0, stream>>>(
        xw, wqkv, nullptr, nullptr, nullptr, qkvbuf, T_TOK, 1152, C_DIM);

    // 3. MFMA windowed attention -> obuf (bf16)
    attn_mfma_kernel<<<NWIN * NHEADS, 64, 0, stream>>>(qkvbuf, biasmat, obuf);

    // 4. proj = obuf @ proj_w^T + proj_b -> pbuf (fp32)
    gemm_bf16_kernel<1, false><<<dim3(T_TOK / 128, C_DIM / 128), 256, 0, stream>>>(
        obuf, wproj, proj_b, nullptr, nullptr, pbuf, T_TOK, C_DIM, C_DIM);

    // 5. window reverse + residual + ls1 -> d_out (= x1, fp32)
    reverse_residual_kernel<<<(T_TOK * 96 + 255) / 256, 256, 0, stream>>>(
        x, pbuf, ls1, out);

    // 6. LN2 -> hbuf (bf16)
    ln_kernel<false, true><<<(T_TOK * 64 + 255) / 256, 256, 0, stream>>>(out, n2g, n2b, hbuf);

    // 7. hidden = gelu(hbuf @ fc1_w^T + fc1_b) -> bf16 (N=1536)
    gemm_bf16_kernel<2, true><<<dim3(T_TOK / 128, 1536 / 128), 256, 0, stream>>>(
        hbuf, wfc1, fc1_b, nullptr, nullptr, hidden, T_TOK, 1536, C_DIM);

    // 8. d_out = x1 + ls2 * (hidden @ fc2_w^T + fc2_b)  (K=1536)
    gemm_bf16_kernel<3, false><<<dim3(T_TOK / 128, C_DIM / 128), 256, 0, stream>>>(
        hidden, wfc2, fc2_b, out, ls2, out, T_TOK, C_DIM, 1536);
}

// Round 5
// 377.782 us; speedup vs baseline: 5.4917x; 1.1279x over previous
//
#include <hip/hip_runtime.h>
#include <hip/hip_bf16.h>
#include <math.h>

// Swin block: B=8, H=W=56, C=384, ws=7, nh=12
#define T_TOK 25088   // B * L
#define L_DIM 3136
#define C_DIM 384
#define NHEADS 12
#define HDIM 32
#define NWIN 512
#define NTOK 49

typedef __attribute__((ext_vector_type(8))) short bf16x8_t;   // MFMA A/B frag (4 VGPRs)
typedef __attribute__((ext_vector_type(4))) float f32x4;      // MFMA C/D frag

__device__ __forceinline__ float bf2f(unsigned short u) {
    return __uint_as_float(((unsigned)u) << 16);
}
__device__ __forceinline__ unsigned short f2bf(float f) {
    __hip_bfloat16 h = __float2bfloat16(f);   // RNE
    return *(unsigned short*)&h;
}
// Fast gelu: x*sigmoid(1.702x). |err| <= ~1e-2 vs exact erf-gelu; the MLP
// branch is scaled by ls2=1e-5 before entering the output, so final
// contribution <= ~2e-7 (threshold 0.108). ~5 VALU insts vs ~25 for erff.
__device__ __forceinline__ float gelu_fast(float x) {
    return x / (1.0f + __expf(-1.702f * x));
}

// async global->LDS, 16B per lane; LDS dest must be wave-uniform base + lane*16
__device__ __forceinline__ void gload_lds16(const unsigned short* g, unsigned short* l) {
    __builtin_amdgcn_global_load_lds(
        (const __attribute__((address_space(1))) unsigned int*)(const void*)g,
        (__attribute__((address_space(3))) unsigned int*)(void*)l,
        16, 0, 0);
}

// ---------------------------------------------------------------------------
// Fused fp32 -> bf16 weight conversion. dst = [qkv(442368 f4) | proj | fc1 | fc2]
// ---------------------------------------------------------------------------
__global__ __launch_bounds__(256) void convert_weights_kernel(
    const float* __restrict__ qw, const float* __restrict__ kvw,
    const float* __restrict__ pw, const float* __restrict__ f1,
    const float* __restrict__ f2, unsigned short* __restrict__ dst)
{
    int i = blockIdx.x * 256 + threadIdx.x;   // total 442368 float4s
    if (i >= 442368) return;
    const float* src; int off;
    if      (i < 36864)  { src = qw;  off = i;          }
    else if (i < 110592) { src = kvw; off = i - 36864;  }
    else if (i < 147456) { src = pw;  off = i - 110592; }
    else if (i < 294912) { src = f1;  off = i - 147456; }
    else                 { src = f2;  off = i - 294912; }
    float4 v = ((const float4*)src)[off];
    unsigned short* d = dst + (size_t)i * 4;
    d[0] = f2bf(v.x); d[1] = f2bf(v.y); d[2] = f2bf(v.z); d[3] = f2bf(v.w);
}

// ---------------------------------------------------------------------------
// Pre-expand relative-position bias: biasmat[h][n][m], 12*49*49 floats.
// ---------------------------------------------------------------------------
__global__ __launch_bounds__(256) void bias_precompute_kernel(
    const float* __restrict__ table, float* __restrict__ biasmat)
{
    int e = blockIdx.x * 256 + threadIdx.x;   // 28812 total
    if (e >= 28812) return;
    int h = e / 2401, r = e % 2401;
    int n = r / 49, m = r % 49;
    int i1 = n / 7, j1 = n % 7, i2 = m / 7, j2 = m % 7;
    int idx = (i1 - i2 + 6) * 13 + (j1 - j2 + 6);
    biasmat[e] = table[idx * NHEADS + h];
}

// ---------------------------------------------------------------------------
// LayerNorm, one wave per token row of 384. WINDOWED scatters to window layout.
// ---------------------------------------------------------------------------
template<bool WINDOWED, bool OUTB>
__global__ __launch_bounds__(256) void ln_kernel(
    const float* __restrict__ x, const float* __restrict__ g,
    const float* __restrict__ b, void* __restrict__ yv)
{
    int gid  = blockIdx.x * 256 + threadIdx.x;
    int t    = gid >> 6;
    int lane = threadIdx.x & 63;
    if (t >= T_TOK) return;

    const float* row = x + (size_t)t * C_DIM;
    float vals[6];
    float s = 0.f, s2 = 0.f;
#pragma unroll
    for (int i = 0; i < 6; ++i) {
        float v = row[lane + i * 64];
        vals[i] = v; s += v; s2 += v * v;
    }
#pragma unroll
    for (int off = 32; off; off >>= 1) {
        s  += __shfl_down(s, off);
        s2 += __shfl_down(s2, off);
    }
    s  = __shfl(s, 0);
    s2 = __shfl(s2, 0);
    float mean = s * (1.0f / C_DIM);
    float var  = s2 * (1.0f / C_DIM) - mean * mean;
    float rstd = rsqrtf(var + 1e-5f);

    size_t orow;
    if (WINDOWED) {
        int bb = t / L_DIM, l = t % L_DIM;
        int hr = l / 56, wc = l % 56;
        int w  = (bb * 8 + hr / 7) * 8 + wc / 7;
        int n  = (hr % 7) * 7 + (wc % 7);
        orow = ((size_t)w * NTOK + n) * C_DIM;
    } else {
        orow = (size_t)t * C_DIM;
    }
#pragma unroll
    for (int i = 0; i < 6; ++i) {
        int c = lane + i * 64;
        float o = (vals[i] - mean) * rstd * g[c] + b[c];
        if (OUTB) ((unsigned short*)yv)[orow + c] = f2bf(o);
        else      ((float*)yv)[orow + c] = o;
    }
}

// ---------------------------------------------------------------------------
// bf16 MFMA GEMM: Y[M x Nn] = X[M x K] @ W[Nn x K]^T, 128x128 tile, BK=32,
// 4 waves, global_load_lds staging, bijective XCD swizzle.
// EPI: 0=none 1=+bias 2=gelu_fast(y+bias) 3=res + ls*(y+bias)
// WINREV: epilogue maps window-row -> token-row (fuses window reverse);
//         res/Y are indexed in token layout.
// Epilogue is LDS-staged for coalesced 16B/lane stores (R4: scattered 2B
// stores caused 2x write amplification, 164 vs 77 MB, and VALUBusy 57%).
// ---------------------------------------------------------------------------
template<int EPI, bool OUTB, bool WINREV>
__global__ __launch_bounds__(256) void gemm_bf16_kernel(
    const unsigned short* __restrict__ X, const unsigned short* __restrict__ W,
    const float* __restrict__ bias, const float* __restrict__ res,
    const float* __restrict__ ls, void* __restrict__ Yv,
    int M, int Nn, int K)
{
    // smem: K-loop uses [0,16384) as As/Bs; epilogue reuses it as
    // fp32 staging [2 stripes][16 rows][132 cols] = 16896 B.
    __shared__ __align__(16) char smem[16896];
    unsigned short* As = (unsigned short*)smem;            // 8 KB
    unsigned short* Bs = (unsigned short*)(smem + 8192);   // 8 KB
    float* cs = (float*)smem;

    // XCD-aware bijective swizzle (m204)
    int Nt  = gridDim.y;
    int nwg = gridDim.x * Nt;
    int id  = blockIdx.y * gridDim.x + blockIdx.x;
    int qq  = nwg >> 3, rr = nwg & 7;
    int xcd = id & 7, pos = id >> 3;
    int swz = (xcd < rr) ? (xcd * (qq + 1) + pos)
                         : (rr * (qq + 1) + (xcd - rr) * qq + pos);
    int m0 = (swz / Nt) * 128, n0 = (swz % Nt) * 128;

    int tid  = threadIdx.x;
    int wave = tid >> 6, lane = tid & 63;
    int wr   = wave >> 1, wc = wave & 1;
    int lrow = lane & 15;
    int lk   = (lane >> 4) << 3;

    int srow = tid >> 2;
    int scol = (tid & 3) << 3;

    f32x4 acc[4][4] = {};

    for (int k0 = 0; k0 < K; k0 += 32) {
        gload_lds16(X + (size_t)(m0 + srow) * K + k0 + scol,      As + tid * 8);
        gload_lds16(X + (size_t)(m0 + 64 + srow) * K + k0 + scol, As + 2048 + tid * 8);
        gload_lds16(W + (size_t)(n0 + srow) * K + k0 + scol,      Bs + tid * 8);
        gload_lds16(W + (size_t)(n0 + 64 + srow) * K + k0 + scol, Bs + 2048 + tid * 8);
        __syncthreads();

        bf16x8_t av[4], bv[4];
#pragma unroll
        for (int i = 0; i < 4; ++i)
            av[i] = *(const bf16x8_t*)&As[(wr * 64 + i * 16 + lrow) * 32 + lk];
#pragma unroll
        for (int j = 0; j < 4; ++j)
            bv[j] = *(const bf16x8_t*)&Bs[(wc * 64 + j * 16 + lrow) * 32 + lk];
#pragma unroll
        for (int i = 0; i < 4; ++i)
#pragma unroll
            for (int j = 0; j < 4; ++j)
                acc[i][j] = __builtin_amdgcn_mfma_f32_16x16x32_bf16(
                    av[i], bv[j], acc[i][j], 0, 0, 0);
        __syncthreads();
    }

    // ---- LDS-staged epilogue: 4 stripes of 32 rows x 128 cols ----
#pragma unroll
    for (int i = 0; i < 4; ++i) {
        // write phase: scatter this i-stripe's acc into staging
#pragma unroll
        for (int j = 0; j < 4; ++j)
#pragma unroll
            for (int q = 0; q < 4; ++q)
                cs[(wr * 16 + ((lane >> 4) << 2) + q) * 132 + wc * 64 + j * 16 + lrow]
                    = acc[i][j][q];
        __syncthreads();
        // read phase: 2 passes x 256 threads, 8 contiguous cols per thread
#pragma unroll
        for (int p = 0; p < 2; ++p) {
            int eidx = p * 256 + tid;
            int row  = eidx >> 4;          // 0..31
            int cg   = (eidx & 15) << 3;   // col group start
            int s    = row >> 4, r = row & 15;
            float v[8];
#pragma unroll
            for (int u = 0; u < 8; ++u) v[u] = cs[(s * 16 + r) * 132 + cg + u];
            int col0 = n0 + cg;
            if (EPI >= 1) {
#pragma unroll
                for (int u = 0; u < 8; ++u) v[u] += bias[col0 + u];
            }
            if (EPI == 2) {
#pragma unroll
                for (int u = 0; u < 8; ++u) v[u] = gelu_fast(v[u]);
            }
            int grow = m0 + s * 64 + i * 16 + r;
            size_t orow;
            if (WINREV) {
                int w = grow / 49, n = grow % 49;
                int bb = w >> 6, rem = w & 63;
                int t = bb * L_DIM + ((rem >> 3) * 7 + n / 7) * 56 + (rem & 7) * 7 + n % 7;
                orow = (size_t)t * Nn;
            } else {
                orow = (size_t)grow * Nn;
            }
            if (EPI == 3) {
#pragma unroll
                for (int u = 0; u < 8; ++u)
                    v[u] = res[orow + col0 + u] + ls[col0 + u] * v[u];
            }
            if (OUTB) {
                bf16x8_t pk;
#pragma unroll
                for (int u = 0; u < 8; ++u) pk[u] = (short)f2bf(v[u]);
                *(bf16x8_t*)((unsigned short*)Yv + orow + col0) = pk;
            } else {
                float4 a = make_float4(v[0], v[1], v[2], v[3]);
                float4 b = make_float4(v[4], v[5], v[6], v[7]);
                *(float4*)((float*)Yv + orow + col0)     = a;
                *(float4*)((float*)Yv + orow + col0 + 4) = b;
            }
        }
        __syncthreads();
    }
}

// ---------------------------------------------------------------------------
// MFMA windowed attention: ONE WAVE per (window, head). N=49 padded to 64,
// hd=32 = one K-step of mfma_f32_16x16x32_bf16. (See R3/R4 notes: V pad rows
// zeroed, pad-row bias finite, pad-col bias -inf.)
// ---------------------------------------------------------------------------
__global__ __launch_bounds__(64) void attn_mfma_kernel(
    const unsigned short* __restrict__ qkv,
    const float* __restrict__ biasmat,   // [12][49][49]
    unsigned short* __restrict__ o)
{
    __shared__ unsigned short vs[64 * 40];   // V rows, stride 40 (bank stagger)
    __shared__ unsigned short ps[64 * 64];   // P, XOR-swizzled rows of 128B

    int w    = blockIdx.x / NHEADS;
    int h    = blockIdx.x % NHEADS;
    int lane = threadIdx.x;
    int g    = lane >> 4;       // k-chunk group (frag k-offset = g*8)
    int lr   = lane & 15;

    for (int t = lane; t < 196; t += 64) {
        int row = t >> 2, c = t & 3;
        bf16x8_t v = *(const bf16x8_t*)(qkv + ((size_t)w * NTOK + row) * 1152 + 768 + h * HDIM + c * 8);
        *(bf16x8_t*)(vs + row * 40 + c * 8) = v;
    }
    if (lane < 60) {
        int row = 49 + (lane >> 2), c = lane & 3;
        bf16x8_t z = {};
        *(bf16x8_t*)(vs + row * 40 + c * 8) = z;
    }

    bf16x8_t qf[4], kf[4];
#pragma unroll
    for (int i = 0; i < 4; ++i) {
        int qrow = i * 16 + lr; if (qrow > 48) qrow = 0;
        qf[i] = *(const bf16x8_t*)(qkv + ((size_t)w * NTOK + qrow) * 1152 + h * HDIM + g * 8);
        kf[i] = *(const bf16x8_t*)(qkv + ((size_t)w * NTOK + qrow) * 1152 + 384 + h * HDIM + g * 8);
    }

    f32x4 sacc[4][4];
    const f32x4 zf = {0.f, 0.f, 0.f, 0.f};
#pragma unroll
    for (int i = 0; i < 4; ++i)
#pragma unroll
        for (int j = 0; j < 4; ++j)
            sacc[i][j] = __builtin_amdgcn_mfma_f32_16x16x32_bf16(qf[i], kf[j], zf, 0, 0, 0);

    const float scale = 0.17677669529663687f;  // 1/sqrt(32)
    const float* bh = biasmat + h * 2401;
#pragma unroll
    for (int ni = 0; ni < 4; ++ni) {
#pragma unroll
        for (int q = 0; q < 4; ++q) {
            int row = ni * 16 + g * 4 + q;
            float sv[4];
#pragma unroll
            for (int mj = 0; mj < 4; ++mj) {
                int col = lr + mj * 16;
                float bias = (col < NTOK)
                    ? ((row < NTOK) ? bh[row * NTOK + col] : 0.f)
                    : -INFINITY;
                sv[mj] = sacc[ni][mj][q] * scale + bias;
            }
            float mx = fmaxf(fmaxf(sv[0], sv[1]), fmaxf(sv[2], sv[3]));
#pragma unroll
            for (int d = 1; d < 16; d <<= 1) mx = fmaxf(mx, __shfl_xor(mx, d));
            float e[4], sum = 0.f;
#pragma unroll
            for (int mj = 0; mj < 4; ++mj) {
                int col = lr + mj * 16;
                e[mj] = (col < NTOK) ? expf(sv[mj] - mx) : 0.f;
                sum += e[mj];
            }
#pragma unroll
            for (int d = 1; d < 16; d <<= 1) sum += __shfl_xor(sum, d);
            float rinv = 1.f / sum;
#pragma unroll
            for (int mj = 0; mj < 4; ++mj) {
                int col = lr + mj * 16;
                int byteoff = (row * 128 + col * 2) ^ ((row & 7) << 4);
                *(unsigned short*)((char*)ps + byteoff) = f2bf(e[mj] * rinv);
            }
        }
    }
    __syncthreads();

    f32x4 oacc[4][2] = {};
#pragma unroll
    for (int ks = 0; ks < 2; ++ks) {
        bf16x8_t pf[4];
#pragma unroll
        for (int ni = 0; ni < 4; ++ni) {
            int row = ni * 16 + lr;
            int byteoff = (row * 128 + (ks * 32 + g * 8) * 2) ^ ((row & 7) << 4);
            pf[ni] = *(const bf16x8_t*)((char*)ps + byteoff);
        }
        bf16x8_t vf[2];
#pragma unroll
        for (int dj = 0; dj < 2; ++dj) {
#pragma unroll
            for (int j = 0; j < 8; ++j)
                vf[dj][j] = (short)vs[(ks * 32 + g * 8 + j) * 40 + lr + dj * 16];
        }
#pragma unroll
        for (int ni = 0; ni < 4; ++ni)
#pragma unroll
            for (int dj = 0; dj < 2; ++dj)
                oacc[ni][dj] = __builtin_amdgcn_mfma_f32_16x16x32_bf16(
                    pf[ni], vf[dj], oacc[ni][dj], 0, 0, 0);
    }

#pragma unroll
    for (int ni = 0; ni < 4; ++ni) {
#pragma unroll
        for (int q = 0; q < 4; ++q) {
            int row = ni * 16 + g * 4 + q;
            if (row < NTOK) {
#pragma unroll
                for (int dj = 0; dj < 2; ++dj)
                    o[((size_t)w * NTOK + row) * C_DIM + h * HDIM + lr + dj * 16] =
                        f2bf(oacc[ni][dj][q]);
            }
        }
    }
}

// ---------------------------------------------------------------------------
extern "C" void kernel_launch(void* const* d_in, const int* in_sizes, int n_in,
                              void* d_out, int out_size, void* d_ws, size_t ws_size,
                              hipStream_t stream)
{
    const float* x       = (const float*)d_in[0];
    const float* q_w     = (const float*)d_in[1];
    const float* kv_w    = (const float*)d_in[2];
    const float* proj_w  = (const float*)d_in[3];
    const float* proj_b  = (const float*)d_in[4];
    const float* fc1_w   = (const float*)d_in[5];
    const float* fc1_b   = (const float*)d_in[6];
    const float* fc2_w   = (const float*)d_in[7];
    const float* fc2_b   = (const float*)d_in[8];
    const float* n1g     = (const float*)d_in[9];
    const float* n1b     = (const float*)d_in[10];
    const float* n2g     = (const float*)d_in[11];
    const float* n2b     = (const float*)d_in[12];
    const float* ls1     = (const float*)d_in[13];
    const float* ls2     = (const float*)d_in[14];
    const float* btable  = (const float*)d_in[15];

    float* out = (float*)d_out;
    char*  ws  = (char*)d_ws;

    // Workspace layout:
    //   0          qkv bf16 (57.8 MB) -> hidden bf16 (77 MB)
    //   77070336   (free; was pbuf)
    //   115605504  xw bf16 (19.3 MB) -> obuf bf16
    //   134873088  hbuf bf16 (19.3 MB)
    //   154140672  weights bf16 (7.08 MB)
    //   161218560  biasmat fp32 (115 KB)
    unsigned short* qkvbuf = (unsigned short*)(ws);
    unsigned short* hidden = (unsigned short*)(ws);
    unsigned short* xw     = (unsigned short*)(ws + 115605504);
    unsigned short* obuf   = xw;
    unsigned short* hbuf   = (unsigned short*)(ws + 134873088);
    unsigned short* wqkv   = (unsigned short*)(ws + 154140672);
    unsigned short* wproj  = wqkv + 442368;
    unsigned short* wfc1   = wproj + 147456;
    unsigned short* wfc2   = wfc1 + 589824;
    float*          biasmat= (float*)(ws + 161218560);

    // 0. weights -> bf16 ; relative-position bias matrix
    convert_weights_kernel<<<1728, 256, 0, stream>>>(q_w, kv_w, proj_w, fc1_w, fc2_w, wqkv);
    bias_precompute_kernel<<<113, 256, 0, stream>>>(btable, biasmat);

    // 1. LN1 + window partition -> xw (bf16)
    ln_kernel<true, true><<<(T_TOK * 64 + 255) / 256, 256, 0, stream>>>(x, n1g, n1b, xw);

    // 2. fused qkv = xw @ [q_w;kv_w]^T  (M=25088, N=1152, K=384)
    gemm_bf16_kernel<0, true, false><<<dim3(T_TOK / 128, 1152 / 128), 256, 0, stream>>>(
        xw, wqkv, nullptr, nullptr, nullptr, qkvbuf, T_TOK, 1152, C_DIM);

    // 3. MFMA windowed attention -> obuf (bf16)
    attn_mfma_kernel<<<NWIN * NHEADS, 64, 0, stream>>>(qkvbuf, biasmat, obuf);

    // 4. proj + window reverse + residual + ls1 -> d_out (fp32, token layout)
    gemm_bf16_kernel<3, false, true><<<dim3(T_TOK / 128, C_DIM / 128), 256, 0, stream>>>(
        obuf, wproj, proj_b, x, ls1, out, T_TOK, C_DIM, C_DIM);

    // 5. LN2 -> hbuf (bf16)
    ln_kernel<false, true><<<(T_TOK * 64 + 255) / 256, 256, 0, stream>>>(out, n2g, n2b, hbuf);

    // 6. hidden = gelu(hbuf @ fc1_w^T + fc1_b) -> bf16 (N=1536)
    gemm_bf16_kernel<2, true, false><<<dim3(T_TOK / 128, 1536 / 128), 256, 0, stream>>>(
        hbuf, wfc1, fc1_b, nullptr, nullptr, hidden, T_TOK, 1536, C_DIM);

    // 7. d_out = x1 + ls2 * (hidden @ fc2_w^T + fc2_b)  (K=1536)
    gemm_bf16_kernel<3, false, false><<<dim3(T_TOK / 128, C_DIM / 128), 256, 0, stream>>>(
        hidden, wfc2, fc2_b, out, ls2, out, T_TOK, C_DIM, 1536);
}

// Round 6
// 349.545 us; speedup vs baseline: 5.9354x; 1.0808x over previous
//
#include <hip/hip_runtime.h>
#include <hip/hip_bf16.h>
#include <math.h>

// Swin block: B=8, H=W=56, C=384, ws=7, nh=12
#define T_TOK 25088   // B * L
#define L_DIM 3136
#define C_DIM 384
#define NHEADS 12
#define HDIM 32
#define NWIN 512
#define NTOK 49

typedef __attribute__((ext_vector_type(8))) short bf16x8_t;   // MFMA A/B frag (4 VGPRs)
typedef __attribute__((ext_vector_type(4))) float f32x4;      // MFMA C/D frag

__device__ __forceinline__ float bf2f(unsigned short u) {
    return __uint_as_float(((unsigned)u) << 16);
}
__device__ __forceinline__ unsigned short f2bf(float f) {
    __hip_bfloat16 h = __float2bfloat16(f);   // RNE
    return *(unsigned short*)&h;
}
// Fast gelu: x*sigmoid(1.702x). |err| <= ~1e-2 vs exact erf-gelu; the MLP
// branch is scaled by ls2=1e-5 before entering the output, so final
// contribution <= ~2e-7 (threshold 0.108). ~5 VALU insts vs ~25 for erff.
__device__ __forceinline__ float gelu_fast(float x) {
    return x / (1.0f + __expf(-1.702f * x));
}

// async global->LDS, 16B per lane; LDS dest must be wave-uniform base + lane*16
__device__ __forceinline__ void gload_lds16(const unsigned short* g, unsigned short* l) {
    __builtin_amdgcn_global_load_lds(
        (const __attribute__((address_space(1))) unsigned int*)(const void*)g,
        (__attribute__((address_space(3))) unsigned int*)(void*)l,
        16, 0, 0);
}

// ---------------------------------------------------------------------------
// Fused fp32 -> bf16 weight conversion. dst = [qkv(442368 f4) | proj | fc1 | fc2]
// ---------------------------------------------------------------------------
__global__ __launch_bounds__(256) void convert_weights_kernel(
    const float* __restrict__ qw, const float* __restrict__ kvw,
    const float* __restrict__ pw, const float* __restrict__ f1,
    const float* __restrict__ f2, unsigned short* __restrict__ dst)
{
    int i = blockIdx.x * 256 + threadIdx.x;   // total 442368 float4s
    if (i >= 442368) return;
    const float* src; int off;
    if      (i < 36864)  { src = qw;  off = i;          }
    else if (i < 110592) { src = kvw; off = i - 36864;  }
    else if (i < 147456) { src = pw;  off = i - 110592; }
    else if (i < 294912) { src = f1;  off = i - 147456; }
    else                 { src = f2;  off = i - 294912; }
    float4 v = ((const float4*)src)[off];
    unsigned short* d = dst + (size_t)i * 4;
    d[0] = f2bf(v.x); d[1] = f2bf(v.y); d[2] = f2bf(v.z); d[3] = f2bf(v.w);
}

// ---------------------------------------------------------------------------
// Pre-expand relative-position bias: biasmat[h][n][m], 12*49*49 floats.
// ---------------------------------------------------------------------------
__global__ __launch_bounds__(256) void bias_precompute_kernel(
    const float* __restrict__ table, float* __restrict__ biasmat)
{
    int e = blockIdx.x * 256 + threadIdx.x;   // 28812 total
    if (e >= 28812) return;
    int h = e / 2401, r = e % 2401;
    int n = r / 49, m = r % 49;
    int i1 = n / 7, j1 = n % 7, i2 = m / 7, j2 = m % 7;
    int idx = (i1 - i2 + 6) * 13 + (j1 - j2 + 6);
    biasmat[e] = table[idx * NHEADS + h];
}

// ---------------------------------------------------------------------------
// LayerNorm, one wave per token row of 384. WINDOWED scatters to window layout.
// ---------------------------------------------------------------------------
template<bool WINDOWED, bool OUTB>
__global__ __launch_bounds__(256) void ln_kernel(
    const float* __restrict__ x, const float* __restrict__ g,
    const float* __restrict__ b, void* __restrict__ yv)
{
    int gid  = blockIdx.x * 256 + threadIdx.x;
    int t    = gid >> 6;
    int lane = threadIdx.x & 63;
    if (t >= T_TOK) return;

    const float* row = x + (size_t)t * C_DIM;
    float vals[6];
    float s = 0.f, s2 = 0.f;
#pragma unroll
    for (int i = 0; i < 6; ++i) {
        float v = row[lane + i * 64];
        vals[i] = v; s += v; s2 += v * v;
    }
#pragma unroll
    for (int off = 32; off; off >>= 1) {
        s  += __shfl_down(s, off);
        s2 += __shfl_down(s2, off);
    }
    s  = __shfl(s, 0);
    s2 = __shfl(s2, 0);
    float mean = s * (1.0f / C_DIM);
    float var  = s2 * (1.0f / C_DIM) - mean * mean;
    float rstd = rsqrtf(var + 1e-5f);

    size_t orow;
    if (WINDOWED) {
        int bb = t / L_DIM, l = t % L_DIM;
        int hr = l / 56, wc = l % 56;
        int w  = (bb * 8 + hr / 7) * 8 + wc / 7;
        int n  = (hr % 7) * 7 + (wc % 7);
        orow = ((size_t)w * NTOK + n) * C_DIM;
    } else {
        orow = (size_t)t * C_DIM;
    }
#pragma unroll
    for (int i = 0; i < 6; ++i) {
        int c = lane + i * 64;
        float o = (vals[i] - mean) * rstd * g[c] + b[c];
        if (OUTB) ((unsigned short*)yv)[orow + c] = f2bf(o);
        else      ((float*)yv)[orow + c] = o;
    }
}

// ---------------------------------------------------------------------------
// bf16 MFMA GEMM: Y[M x Nn] = X[M x K] @ W[Nn x K]^T, 128x128 tile, BK=32,
// 4 waves, DOUBLE-BUFFERED global_load_lds staging (stage t+1 before
// computing t; one __syncthreads per K-iter whose implicit vmcnt(0) drains
// the prefetch AFTER ~400cy of compute has covered most of the latency).
// Bijective XCD swizzle. EPI: 0=none 1=+bias 2=gelu_fast 3=res+ls*(y+bias).
// WINREV: epilogue maps window-row -> token-row. LDS-staged coalesced
// epilogue (R5: kills 2x write amplification). Epilogue cs aliases the
// staging buffers (protected by the loop's final barrier).
// ---------------------------------------------------------------------------
template<int EPI, bool OUTB, bool WINREV>
__global__ __launch_bounds__(256) void gemm_bf16_kernel(
    const unsigned short* __restrict__ X, const unsigned short* __restrict__ W,
    const float* __restrict__ bias, const float* __restrict__ res,
    const float* __restrict__ ls, void* __restrict__ Yv,
    int M, int Nn, int K)
{
    // [As0 8K | Bs0 8K | As1 8K | Bs1 8K] = 32 KB; epilogue cs = 16896 B union.
    __shared__ __align__(16) char smem[32768];
    unsigned short* As0 = (unsigned short*)smem;
    unsigned short* Bs0 = (unsigned short*)(smem + 8192);
    unsigned short* As1 = (unsigned short*)(smem + 16384);
    unsigned short* Bs1 = (unsigned short*)(smem + 24576);
    float* cs = (float*)smem;

    // XCD-aware bijective swizzle (m204)
    int Nt  = gridDim.y;
    int nwg = gridDim.x * Nt;
    int id  = blockIdx.y * gridDim.x + blockIdx.x;
    int qq  = nwg >> 3, rr = nwg & 7;
    int xcd = id & 7, pos = id >> 3;
    int swz = (xcd < rr) ? (xcd * (qq + 1) + pos)
                         : (rr * (qq + 1) + (xcd - rr) * qq + pos);
    int m0 = (swz / Nt) * 128, n0 = (swz % Nt) * 128;

    int tid  = threadIdx.x;
    int wave = tid >> 6, lane = tid & 63;
    int wr   = wave >> 1, wc = wave & 1;
    int lrow = lane & 15;
    int lk   = (lane >> 4) << 3;

    int srow = tid >> 2;
    int scol = (tid & 3) << 3;

    const unsigned short* Xa = X + (size_t)(m0 + srow) * K + scol;
    const unsigned short* Xb = X + (size_t)(m0 + 64 + srow) * K + scol;
    const unsigned short* Wa = W + (size_t)(n0 + srow) * K + scol;
    const unsigned short* Wb = W + (size_t)(n0 + 64 + srow) * K + scol;

    f32x4 acc[4][4] = {};
    int nt = K >> 5;

    // prologue: stage tile 0
    gload_lds16(Xa, As0 + tid * 8);
    gload_lds16(Xb, As0 + 2048 + tid * 8);
    gload_lds16(Wa, Bs0 + tid * 8);
    gload_lds16(Wb, Bs0 + 2048 + tid * 8);
    __syncthreads();

    for (int t = 0; t < nt; ++t) {
        unsigned short* A  = (t & 1) ? As1 : As0;
        unsigned short* B  = (t & 1) ? Bs1 : Bs0;
        if (t + 1 < nt) {
            unsigned short* An = (t & 1) ? As0 : As1;
            unsigned short* Bn = (t & 1) ? Bs0 : Bs1;
            int k0 = (t + 1) << 5;
            gload_lds16(Xa + k0, An + tid * 8);
            gload_lds16(Xb + k0, An + 2048 + tid * 8);
            gload_lds16(Wa + k0, Bn + tid * 8);
            gload_lds16(Wb + k0, Bn + 2048 + tid * 8);
        }

        bf16x8_t av[4], bv[4];
#pragma unroll
        for (int i = 0; i < 4; ++i)
            av[i] = *(const bf16x8_t*)&A[(wr * 64 + i * 16 + lrow) * 32 + lk];
#pragma unroll
        for (int j = 0; j < 4; ++j)
            bv[j] = *(const bf16x8_t*)&B[(wc * 64 + j * 16 + lrow) * 32 + lk];
#pragma unroll
        for (int i = 0; i < 4; ++i)
#pragma unroll
            for (int j = 0; j < 4; ++j)
                acc[i][j] = __builtin_amdgcn_mfma_f32_16x16x32_bf16(
                    av[i], bv[j], acc[i][j], 0, 0, 0);
        __syncthreads();   // drains next tile's loads; protects buffer reuse
    }

    // ---- LDS-staged epilogue: 4 stripes of 32 rows x 128 cols ----
#pragma unroll
    for (int i = 0; i < 4; ++i) {
#pragma unroll
        for (int j = 0; j < 4; ++j)
#pragma unroll
            for (int q = 0; q < 4; ++q)
                cs[(wr * 16 + ((lane >> 4) << 2) + q) * 132 + wc * 64 + j * 16 + lrow]
                    = acc[i][j][q];
        __syncthreads();
#pragma unroll
        for (int p = 0; p < 2; ++p) {
            int eidx = p * 256 + tid;
            int row  = eidx >> 4;          // 0..31
            int cg   = (eidx & 15) << 3;   // col group start
            int s    = row >> 4, r = row & 15;
            float v[8];
#pragma unroll
            for (int u = 0; u < 8; ++u) v[u] = cs[(s * 16 + r) * 132 + cg + u];
            int col0 = n0 + cg;
            if (EPI >= 1) {
#pragma unroll
                for (int u = 0; u < 8; ++u) v[u] += bias[col0 + u];
            }
            if (EPI == 2) {
#pragma unroll
                for (int u = 0; u < 8; ++u) v[u] = gelu_fast(v[u]);
            }
            int grow = m0 + s * 64 + i * 16 + r;
            size_t orow;
            if (WINREV) {
                int w = grow / 49, n = grow % 49;
                int bb = w >> 6, rem = w & 63;
                int t = bb * L_DIM + ((rem >> 3) * 7 + n / 7) * 56 + (rem & 7) * 7 + n % 7;
                orow = (size_t)t * Nn;
            } else {
                orow = (size_t)grow * Nn;
            }
            if (EPI == 3) {
#pragma unroll
                for (int u = 0; u < 8; ++u)
                    v[u] = res[orow + col0 + u] + ls[col0 + u] * v[u];
            }
            if (OUTB) {
                bf16x8_t pk;
#pragma unroll
                for (int u = 0; u < 8; ++u) pk[u] = (short)f2bf(v[u]);
                *(bf16x8_t*)((unsigned short*)Yv + orow + col0) = pk;
            } else {
                float4 a = make_float4(v[0], v[1], v[2], v[3]);
                float4 b = make_float4(v[4], v[5], v[6], v[7]);
                *(float4*)((float*)Yv + orow + col0)     = a;
                *(float4*)((float*)Yv + orow + col0 + 4) = b;
            }
        }
        __syncthreads();
    }
}

// ---------------------------------------------------------------------------
// MFMA windowed attention: ONE WAVE per (window, head). N=49 padded to 64,
// hd=32 = one K-step of mfma_f32_16x16x32_bf16. (V pad rows zeroed,
// pad-row bias finite, pad-col bias -inf — R3/R4 NaN hygiene.)
// ---------------------------------------------------------------------------
__global__ __launch_bounds__(64) void attn_mfma_kernel(
    const unsigned short* __restrict__ qkv,
    const float* __restrict__ biasmat,   // [12][49][49]
    unsigned short* __restrict__ o)
{
    __shared__ unsigned short vs[64 * 40];   // V rows, stride 40 (bank stagger)
    __shared__ unsigned short ps[64 * 64];   // P, XOR-swizzled rows of 128B

    int w    = blockIdx.x / NHEADS;
    int h    = blockIdx.x % NHEADS;
    int lane = threadIdx.x;
    int g    = lane >> 4;       // k-chunk group (frag k-offset = g*8)
    int lr   = lane & 15;

    for (int t = lane; t < 196; t += 64) {
        int row = t >> 2, c = t & 3;
        bf16x8_t v = *(const bf16x8_t*)(qkv + ((size_t)w * NTOK + row) * 1152 + 768 + h * HDIM + c * 8);
        *(bf16x8_t*)(vs + row * 40 + c * 8) = v;
    }
    if (lane < 60) {
        int row = 49 + (lane >> 2), c = lane & 3;
        bf16x8_t z = {};
        *(bf16x8_t*)(vs + row * 40 + c * 8) = z;
    }

    bf16x8_t qf[4], kf[4];
#pragma unroll
    for (int i = 0; i < 4; ++i) {
        int qrow = i * 16 + lr; if (qrow > 48) qrow = 0;
        qf[i] = *(const bf16x8_t*)(qkv + ((size_t)w * NTOK + qrow) * 1152 + h * HDIM + g * 8);
        kf[i] = *(const bf16x8_t*)(qkv + ((size_t)w * NTOK + qrow) * 1152 + 384 + h * HDIM + g * 8);
    }

    f32x4 sacc[4][4];
    const f32x4 zf = {0.f, 0.f, 0.f, 0.f};
#pragma unroll
    for (int i = 0; i < 4; ++i)
#pragma unroll
        for (int j = 0; j < 4; ++j)
            sacc[i][j] = __builtin_amdgcn_mfma_f32_16x16x32_bf16(qf[i], kf[j], zf, 0, 0, 0);

    const float scale = 0.17677669529663687f;  // 1/sqrt(32)
    const float* bh = biasmat + h * 2401;
#pragma unroll
    for (int ni = 0; ni < 4; ++ni) {
#pragma unroll
        for (int q = 0; q < 4; ++q) {
            int row = ni * 16 + g * 4 + q;
            float sv[4];
#pragma unroll
            for (int mj = 0; mj < 4; ++mj) {
                int col = lr + mj * 16;
                float bias = (col < NTOK)
                    ? ((row < NTOK) ? bh[row * NTOK + col] : 0.f)
                    : -INFINITY;
                sv[mj] = sacc[ni][mj][q] * scale + bias;
            }
            float mx = fmaxf(fmaxf(sv[0], sv[1]), fmaxf(sv[2], sv[3]));
#pragma unroll
            for (int d = 1; d < 16; d <<= 1) mx = fmaxf(mx, __shfl_xor(mx, d));
            float e[4], sum = 0.f;
#pragma unroll
            for (int mj = 0; mj < 4; ++mj) {
                int col = lr + mj * 16;
                e[mj] = (col < NTOK) ? expf(sv[mj] - mx) : 0.f;
                sum += e[mj];
            }
#pragma unroll
            for (int d = 1; d < 16; d <<= 1) sum += __shfl_xor(sum, d);
            float rinv = 1.f / sum;
#pragma unroll
            for (int mj = 0; mj < 4; ++mj) {
                int col = lr + mj * 16;
                int byteoff = (row * 128 + col * 2) ^ ((row & 7) << 4);
                *(unsigned short*)((char*)ps + byteoff) = f2bf(e[mj] * rinv);
            }
        }
    }
    __syncthreads();

    f32x4 oacc[4][2] = {};
#pragma unroll
    for (int ks = 0; ks < 2; ++ks) {
        bf16x8_t pf[4];
#pragma unroll
        for (int ni = 0; ni < 4; ++ni) {
            int row = ni * 16 + lr;
            int byteoff = (row * 128 + (ks * 32 + g * 8) * 2) ^ ((row & 7) << 4);
            pf[ni] = *(const bf16x8_t*)((char*)ps + byteoff);
        }
        bf16x8_t vf[2];
#pragma unroll
        for (int dj = 0; dj < 2; ++dj) {
#pragma unroll
            for (int j = 0; j < 8; ++j)
                vf[dj][j] = (short)vs[(ks * 32 + g * 8 + j) * 40 + lr + dj * 16];
        }
#pragma unroll
        for (int ni = 0; ni < 4; ++ni)
#pragma unroll
            for (int dj = 0; dj < 2; ++dj)
                oacc[ni][dj] = __builtin_amdgcn_mfma_f32_16x16x32_bf16(
                    pf[ni], vf[dj], oacc[ni][dj], 0, 0, 0);
    }

#pragma unroll
    for (int ni = 0; ni < 4; ++ni) {
#pragma unroll
        for (int q = 0; q < 4; ++q) {
            int row = ni * 16 + g * 4 + q;
            if (row < NTOK) {
#pragma unroll
                for (int dj = 0; dj < 2; ++dj)
                    o[((size_t)w * NTOK + row) * C_DIM + h * HDIM + lr + dj * 16] =
                        f2bf(oacc[ni][dj][q]);
            }
        }
    }
}

// ---------------------------------------------------------------------------
extern "C" void kernel_launch(void* const* d_in, const int* in_sizes, int n_in,
                              void* d_out, int out_size, void* d_ws, size_t ws_size,
                              hipStream_t stream)
{
    const float* x       = (const float*)d_in[0];
    const float* q_w     = (const float*)d_in[1];
    const float* kv_w    = (const float*)d_in[2];
    const float* proj_w  = (const float*)d_in[3];
    const float* proj_b  = (const float*)d_in[4];
    const float* fc1_w   = (const float*)d_in[5];
    const float* fc1_b   = (const float*)d_in[6];
    const float* fc2_w   = (const float*)d_in[7];
    const float* fc2_b   = (const float*)d_in[8];
    const float* n1g     = (const float*)d_in[9];
    const float* n1b     = (const float*)d_in[10];
    const float* n2g     = (const float*)d_in[11];
    const float* n2b     = (const float*)d_in[12];
    const float* ls1     = (const float*)d_in[13];
    const float* ls2     = (const float*)d_in[14];
    const float* btable  = (const float*)d_in[15];

    float* out = (float*)d_out;
    char*  ws  = (char*)d_ws;

    // Workspace layout:
    //   0          qkv bf16 (57.8 MB) -> hidden bf16 (77 MB)
    //   115605504  xw bf16 (19.3 MB) -> obuf bf16
    //   134873088  hbuf bf16 (19.3 MB)
    //   154140672  weights bf16 (7.08 MB)
    //   161218560  biasmat fp32 (115 KB)
    unsigned short* qkvbuf = (unsigned short*)(ws);
    unsigned short* hidden = (unsigned short*)(ws);
    unsigned short* xw     = (unsigned short*)(ws + 115605504);
    unsigned short* obuf   = xw;
    unsigned short* hbuf   = (unsigned short*)(ws + 134873088);
    unsigned short* wqkv   = (unsigned short*)(ws + 154140672);
    unsigned short* wproj  = wqkv + 442368;
    unsigned short* wfc1   = wproj + 147456;
    unsigned short* wfc2   = wfc1 + 589824;
    float*          biasmat= (float*)(ws + 161218560);

    // 0. weights -> bf16 ; relative-position bias matrix
    convert_weights_kernel<<<1728, 256, 0, stream>>>(q_w, kv_w, proj_w, fc1_w, fc2_w, wqkv);
    bias_precompute_kernel<<<113, 256, 0, stream>>>(btable, biasmat);

    // 1. LN1 + window partition -> xw (bf16)
    ln_kernel<true, true><<<(T_TOK * 64 + 255) / 256, 256, 0, stream>>>(x, n1g, n1b, xw);

    // 2. fused qkv = xw @ [q_w;kv_w]^T  (M=25088, N=1152, K=384)
    gemm_bf16_kernel<0, true, false><<<dim3(T_TOK / 128, 1152 / 128), 256, 0, stream>>>(
        xw, wqkv, nullptr, nullptr, nullptr, qkvbuf, T_TOK, 1152, C_DIM);

    // 3. MFMA windowed attention -> obuf (bf16)
    attn_mfma_kernel<<<NWIN * NHEADS, 64, 0, stream>>>(qkvbuf, biasmat, obuf);

    // 4. proj + window reverse + residual + ls1 -> d_out (fp32, token layout)
    gemm_bf16_kernel<3, false, true><<<dim3(T_TOK / 128, C_DIM / 128), 256, 0, stream>>>(
        obuf, wproj, proj_b, x, ls1, out, T_TOK, C_DIM, C_DIM);

    // 5. LN2 -> hbuf (bf16)
    ln_kernel<false, true><<<(T_TOK * 64 + 255) / 256, 256, 0, stream>>>(out, n2g, n2b, hbuf);

    // 6. hidden = gelu(hbuf @ fc1_w^T + fc1_b) -> bf16 (N=1536)
    gemm_bf16_kernel<2, true, false><<<dim3(T_TOK / 128, 1536 / 128), 256, 0, stream>>>(
        hbuf, wfc1, fc1_b, nullptr, nullptr, hidden, T_TOK, 1536, C_DIM);

    // 7. d_out = x1 + ls2 * (hidden @ fc2_w^T + fc2_b)  (K=1536)
    gemm_bf16_kernel<3, false, false><<<dim3(T_TOK / 128, C_DIM / 128), 256, 0, stream>>>(
        hidden, wfc2, fc2_b, out, ls2, out, T_TOK, C_DIM, 1536);
}

// Round 7
// 340.373 us; speedup vs baseline: 6.0953x; 1.0269x over previous
//
#include <hip/hip_runtime.h>
#include <hip/hip_bf16.h>
#include <math.h>

// Swin block: B=8, H=W=56, C=384, ws=7, nh=12
#define T_TOK 25088   // B * L
#define L_DIM 3136
#define C_DIM 384
#define NHEADS 12
#define HDIM 32
#define NWIN 512
#define NTOK 49

typedef __attribute__((ext_vector_type(8))) short bf16x8_t;   // MFMA A/B frag (4 VGPRs)
typedef __attribute__((ext_vector_type(4))) float f32x4;      // MFMA C/D frag

__device__ __forceinline__ float bf2f(unsigned short u) {
    return __uint_as_float(((unsigned)u) << 16);
}
__device__ __forceinline__ unsigned short f2bf(float f) {
    __hip_bfloat16 h = __float2bfloat16(f);   // RNE
    return *(unsigned short*)&h;
}
// Fast gelu: x*sigmoid(1.702x). MLP branch scaled by ls2=1e-5 -> final err ~2e-7.
__device__ __forceinline__ float gelu_fast(float x) {
    return x / (1.0f + __expf(-1.702f * x));
}

// async global->LDS, 16B per lane; LDS dest must be wave-uniform base + lane*16
__device__ __forceinline__ void gload_lds16(const unsigned short* g, unsigned short* l) {
    __builtin_amdgcn_global_load_lds(
        (const __attribute__((address_space(1))) unsigned int*)(const void*)g,
        (__attribute__((address_space(3))) unsigned int*)(void*)l,
        16, 0, 0);
}

// ---------------------------------------------------------------------------
// Fused fp32 -> bf16 weight conversion. dst = [qkv(442368 f4) | proj | fc1 | fc2]
// ---------------------------------------------------------------------------
__global__ __launch_bounds__(256) void convert_weights_kernel(
    const float* __restrict__ qw, const float* __restrict__ kvw,
    const float* __restrict__ pw, const float* __restrict__ f1,
    const float* __restrict__ f2, unsigned short* __restrict__ dst)
{
    int i = blockIdx.x * 256 + threadIdx.x;   // total 442368 float4s
    if (i >= 442368) return;
    const float* src; int off;
    if      (i < 36864)  { src = qw;  off = i;          }
    else if (i < 110592) { src = kvw; off = i - 36864;  }
    else if (i < 147456) { src = pw;  off = i - 110592; }
    else if (i < 294912) { src = f1;  off = i - 147456; }
    else                 { src = f2;  off = i - 294912; }
    float4 v = ((const float4*)src)[off];
    unsigned short* d = dst + (size_t)i * 4;
    d[0] = f2bf(v.x); d[1] = f2bf(v.y); d[2] = f2bf(v.z); d[3] = f2bf(v.w);
}

// ---------------------------------------------------------------------------
// Pre-expand relative-position bias to bf16: biasmat16[h][n*52+m], head
// stride 2560 ushorts (5120 B, room for 16B-chunked async staging).
// ---------------------------------------------------------------------------
__global__ __launch_bounds__(256) void bias_precompute_kernel(
    const float* __restrict__ table, unsigned short* __restrict__ biasmat16)
{
    int e = blockIdx.x * 256 + threadIdx.x;   // 28812 total
    if (e >= 28812) return;
    int h = e / 2401, r = e % 2401;
    int n = r / 49, m = r % 49;
    int i1 = n / 7, j1 = n % 7, i2 = m / 7, j2 = m % 7;
    int idx = (i1 - i2 + 6) * 13 + (j1 - j2 + 6);
    biasmat16[h * 2560 + n * 52 + m] = f2bf(table[idx * NHEADS + h]);
}

// ---------------------------------------------------------------------------
// LayerNorm, one wave per token row of 384. WINDOWED scatters to window layout.
// ---------------------------------------------------------------------------
template<bool WINDOWED, bool OUTB>
__global__ __launch_bounds__(256) void ln_kernel(
    const float* __restrict__ x, const float* __restrict__ g,
    const float* __restrict__ b, void* __restrict__ yv)
{
    int gid  = blockIdx.x * 256 + threadIdx.x;
    int t    = gid >> 6;
    int lane = threadIdx.x & 63;
    if (t >= T_TOK) return;

    const float* row = x + (size_t)t * C_DIM;
    float vals[6];
    float s = 0.f, s2 = 0.f;
#pragma unroll
    for (int i = 0; i < 6; ++i) {
        float v = row[lane + i * 64];
        vals[i] = v; s += v; s2 += v * v;
    }
#pragma unroll
    for (int off = 32; off; off >>= 1) {
        s  += __shfl_down(s, off);
        s2 += __shfl_down(s2, off);
    }
    s  = __shfl(s, 0);
    s2 = __shfl(s2, 0);
    float mean = s * (1.0f / C_DIM);
    float var  = s2 * (1.0f / C_DIM) - mean * mean;
    float rstd = rsqrtf(var + 1e-5f);

    size_t orow;
    if (WINDOWED) {
        int bb = t / L_DIM, l = t % L_DIM;
        int hr = l / 56, wc = l % 56;
        int w  = (bb * 8 + hr / 7) * 8 + wc / 7;
        int n  = (hr % 7) * 7 + (wc % 7);
        orow = ((size_t)w * NTOK + n) * C_DIM;
    } else {
        orow = (size_t)t * C_DIM;
    }
#pragma unroll
    for (int i = 0; i < 6; ++i) {
        int c = lane + i * 64;
        float o = (vals[i] - mean) * rstd * g[c] + b[c];
        if (OUTB) ((unsigned short*)yv)[orow + c] = f2bf(o);
        else      ((float*)yv)[orow + c] = o;
    }
}

// ---------------------------------------------------------------------------
// bf16 MFMA GEMM: 128x128 tile, BK=32, 4 waves, double-buffered
// global_load_lds staging, bijective XCD swizzle, LDS-staged epilogue.
// EPI: 0=none 1=+bias 2=gelu_fast 3=res+ls*(y+bias). WINREV: window->token.
// ---------------------------------------------------------------------------
template<int EPI, bool OUTB, bool WINREV>
__global__ __launch_bounds__(256) void gemm_bf16_kernel(
    const unsigned short* __restrict__ X, const unsigned short* __restrict__ W,
    const float* __restrict__ bias, const float* __restrict__ res,
    const float* __restrict__ ls, void* __restrict__ Yv,
    int M, int Nn, int K)
{
    __shared__ __align__(16) char smem[32768];
    unsigned short* As0 = (unsigned short*)smem;
    unsigned short* Bs0 = (unsigned short*)(smem + 8192);
    unsigned short* As1 = (unsigned short*)(smem + 16384);
    unsigned short* Bs1 = (unsigned short*)(smem + 24576);
    float* cs = (float*)smem;

    int Nt  = gridDim.y;
    int nwg = gridDim.x * Nt;
    int id  = blockIdx.y * gridDim.x + blockIdx.x;
    int qq  = nwg >> 3, rr = nwg & 7;
    int xcd = id & 7, pos = id >> 3;
    int swz = (xcd < rr) ? (xcd * (qq + 1) + pos)
                         : (rr * (qq + 1) + (xcd - rr) * qq + pos);
    int m0 = (swz / Nt) * 128, n0 = (swz % Nt) * 128;

    int tid  = threadIdx.x;
    int wave = tid >> 6, lane = tid & 63;
    int wr   = wave >> 1, wc = wave & 1;
    int lrow = lane & 15;
    int lk   = (lane >> 4) << 3;

    int srow = tid >> 2;
    int scol = (tid & 3) << 3;

    const unsigned short* Xa = X + (size_t)(m0 + srow) * K + scol;
    const unsigned short* Xb = X + (size_t)(m0 + 64 + srow) * K + scol;
    const unsigned short* Wa = W + (size_t)(n0 + srow) * K + scol;
    const unsigned short* Wb = W + (size_t)(n0 + 64 + srow) * K + scol;

    f32x4 acc[4][4] = {};
    int nt = K >> 5;

    gload_lds16(Xa, As0 + tid * 8);
    gload_lds16(Xb, As0 + 2048 + tid * 8);
    gload_lds16(Wa, Bs0 + tid * 8);
    gload_lds16(Wb, Bs0 + 2048 + tid * 8);
    __syncthreads();

    for (int t = 0; t < nt; ++t) {
        unsigned short* A  = (t & 1) ? As1 : As0;
        unsigned short* B  = (t & 1) ? Bs1 : Bs0;
        if (t + 1 < nt) {
            unsigned short* An = (t & 1) ? As0 : As1;
            unsigned short* Bn = (t & 1) ? Bs0 : Bs1;
            int k0 = (t + 1) << 5;
            gload_lds16(Xa + k0, An + tid * 8);
            gload_lds16(Xb + k0, An + 2048 + tid * 8);
            gload_lds16(Wa + k0, Bn + tid * 8);
            gload_lds16(Wb + k0, Bn + 2048 + tid * 8);
        }

        bf16x8_t av[4], bv[4];
#pragma unroll
        for (int i = 0; i < 4; ++i)
            av[i] = *(const bf16x8_t*)&A[(wr * 64 + i * 16 + lrow) * 32 + lk];
#pragma unroll
        for (int j = 0; j < 4; ++j)
            bv[j] = *(const bf16x8_t*)&B[(wc * 64 + j * 16 + lrow) * 32 + lk];
#pragma unroll
        for (int i = 0; i < 4; ++i)
#pragma unroll
            for (int j = 0; j < 4; ++j)
                acc[i][j] = __builtin_amdgcn_mfma_f32_16x16x32_bf16(
                    av[i], bv[j], acc[i][j], 0, 0, 0);
        __syncthreads();
    }

    // ---- LDS-staged epilogue: 4 stripes of 32 rows x 128 cols ----
#pragma unroll
    for (int i = 0; i < 4; ++i) {
#pragma unroll
        for (int j = 0; j < 4; ++j)
#pragma unroll
            for (int q = 0; q < 4; ++q)
                cs[(wr * 16 + ((lane >> 4) << 2) + q) * 132 + wc * 64 + j * 16 + lrow]
                    = acc[i][j][q];
        __syncthreads();
#pragma unroll
        for (int p = 0; p < 2; ++p) {
            int eidx = p * 256 + tid;
            int row  = eidx >> 4;
            int cg   = (eidx & 15) << 3;
            int s    = row >> 4, r = row & 15;
            float v[8];
#pragma unroll
            for (int u = 0; u < 8; ++u) v[u] = cs[(s * 16 + r) * 132 + cg + u];
            int col0 = n0 + cg;
            if (EPI >= 1) {
#pragma unroll
                for (int u = 0; u < 8; ++u) v[u] += bias[col0 + u];
            }
            if (EPI == 2) {
#pragma unroll
                for (int u = 0; u < 8; ++u) v[u] = gelu_fast(v[u]);
            }
            int grow = m0 + s * 64 + i * 16 + r;
            size_t orow;
            if (WINREV) {
                int w = grow / 49, n = grow % 49;
                int bb = w >> 6, rem = w & 63;
                int t = bb * L_DIM + ((rem >> 3) * 7 + n / 7) * 56 + (rem & 7) * 7 + n % 7;
                orow = (size_t)t * Nn;
            } else {
                orow = (size_t)grow * Nn;
            }
            if (EPI == 3) {
#pragma unroll
                for (int u = 0; u < 8; ++u)
                    v[u] = res[orow + col0 + u] + ls[col0 + u] * v[u];
            }
            if (OUTB) {
                bf16x8_t pk;
#pragma unroll
                for (int u = 0; u < 8; ++u) pk[u] = (short)f2bf(v[u]);
                *(bf16x8_t*)((unsigned short*)Yv + orow + col0) = pk;
            } else {
                float4 a = make_float4(v[0], v[1], v[2], v[3]);
                float4 b = make_float4(v[4], v[5], v[6], v[7]);
                *(float4*)((float*)Yv + orow + col0)     = a;
                *(float4*)((float*)Yv + orow + col0 + 4) = b;
            }
        }
        __syncthreads();
    }
}

// ---------------------------------------------------------------------------
// MFMA windowed attention, R7: 2 waves/block = 2 windows x SAME head.
// Latency fixes vs R6 (which was latency-bound: MfmaUtil 1.4%, VALU 24%):
//  - bias tile (bf16, stride 52) async-staged to LDS via global_load_lds,
//    issued FIRST; softmax reads it with ~6cy ds_read instead of serial
//    ~200cy L2 scalar loads.
//  - T14 split V staging: V->regs issued before Q/K loads; regs->LDS after.
//    (R6 did load->ds_write per chunk, serializing a full HBM round trip
//    before Q/K even issued.)
//  - one block barrier (covers cross-wave bias hazard); vs/ps are per-wave
//    so within-wave lgkmcnt ordering suffices for them.
// LDS 31.7 KB/block -> 5 blocks/CU = 10 waves/CU (was 8).
// NaN hygiene from R4 kept: V pad rows zeroed, pad-row bias finite,
// pad-col bias -inf.
// ---------------------------------------------------------------------------
__global__ __launch_bounds__(128) void attn_mfma_kernel(
    const unsigned short* __restrict__ qkv,
    const unsigned short* __restrict__ biasmat16,   // [12][2560], row stride 52
    unsigned short* __restrict__ o)
{
    __shared__ unsigned short bias_s[2560];        // 5120 B, shared (one head)
    __shared__ unsigned short vs[2][64 * 40];      // per wave
    __shared__ unsigned short ps[2][64 * 64];      // per wave, XOR-swizzled

    int h    = blockIdx.x % NHEADS;
    int w    = (blockIdx.x / NHEADS) * 2 + (threadIdx.x >> 6);
    int lane = threadIdx.x & 63;
    int wave = threadIdx.x >> 6;
    int g    = lane >> 4;       // k-chunk group (frag k-offset = g*8)
    int lr   = lane & 15;

    // ---- 1. bias -> LDS, async, issued first (320 chunks over 2 waves) ----
    const unsigned short* bsrc = biasmat16 + h * 2560;
    {
        int c0 = wave * 64 + lane;
        gload_lds16(bsrc + c0 * 8, bias_s + c0 * 8);
        int c1 = 128 + wave * 64 + lane;
        gload_lds16(bsrc + c1 * 8, bias_s + c1 * 8);
        int c2 = 256 + wave * 64 + lane;
        if (c2 < 320)   // wave-uniform: all of wave 0, none of wave 1
            gload_lds16(bsrc + c2 * 8, bias_s + c2 * 8);
    }

    // ---- 2. V -> registers (issued before Q/K; written to LDS later) ----
    const unsigned short* vbase = qkv + (size_t)w * NTOK * 1152 + 768 + h * HDIM;
    bf16x8_t vreg[4];
#pragma unroll
    for (int k = 0; k < 4; ++k) {
        int t = lane + k * 64;
        if (t < 196)
            vreg[k] = *(const bf16x8_t*)(vbase + (size_t)(t >> 2) * 1152 + (t & 3) * 8);
    }

    // ---- 3. Q, K fragments direct from global (clamp padded rows) ----
    bf16x8_t qf[4], kf[4];
#pragma unroll
    for (int i = 0; i < 4; ++i) {
        int qrow = i * 16 + lr; if (qrow > 48) qrow = 0;
        qf[i] = *(const bf16x8_t*)(qkv + ((size_t)w * NTOK + qrow) * 1152 + h * HDIM + g * 8);
        kf[i] = *(const bf16x8_t*)(qkv + ((size_t)w * NTOK + qrow) * 1152 + 384 + h * HDIM + g * 8);
    }

    // ---- 4. V regs -> LDS; zero pad rows 49..63 ----
#pragma unroll
    for (int k = 0; k < 4; ++k) {
        int t = lane + k * 64;
        if (t < 196)
            *(bf16x8_t*)(vs[wave] + (t >> 2) * 40 + (t & 3) * 8) = vreg[k];
    }
    if (lane < 60) {
        int row = 49 + (lane >> 2), c = lane & 3;
        bf16x8_t z = {};
        *(bf16x8_t*)(vs[wave] + row * 40 + c * 8) = z;
    }

    // ---- 5. S = Q K^T (16 MFMAs, single K-step) ----
    f32x4 sacc[4][4];
    const f32x4 zf = {0.f, 0.f, 0.f, 0.f};
#pragma unroll
    for (int i = 0; i < 4; ++i)
#pragma unroll
        for (int j = 0; j < 4; ++j)
            sacc[i][j] = __builtin_amdgcn_mfma_f32_16x16x32_bf16(qf[i], kf[j], zf, 0, 0, 0);

    // ---- 6. barrier: bias_s complete (vmcnt drained per wave) ----
    __syncthreads();

    // ---- 7. softmax; bias from LDS ----
    const float scale = 0.17677669529663687f;  // 1/sqrt(32)
#pragma unroll
    for (int ni = 0; ni < 4; ++ni) {
#pragma unroll
        for (int q = 0; q < 4; ++q) {
            int row = ni * 16 + g * 4 + q;
            float sv[4];
#pragma unroll
            for (int mj = 0; mj < 4; ++mj) {
                int col = lr + mj * 16;
                float bias = (col < NTOK)
                    ? ((row < NTOK) ? bf2f(bias_s[row * 52 + col]) : 0.f)
                    : -INFINITY;
                sv[mj] = sacc[ni][mj][q] * scale + bias;
            }
            float mx = fmaxf(fmaxf(sv[0], sv[1]), fmaxf(sv[2], sv[3]));
#pragma unroll
            for (int d = 1; d < 16; d <<= 1) mx = fmaxf(mx, __shfl_xor(mx, d));
            float e[4], sum = 0.f;
#pragma unroll
            for (int mj = 0; mj < 4; ++mj) {
                int col = lr + mj * 16;
                e[mj] = (col < NTOK) ? expf(sv[mj] - mx) : 0.f;
                sum += e[mj];
            }
#pragma unroll
            for (int d = 1; d < 16; d <<= 1) sum += __shfl_xor(sum, d);
            float rinv = 1.f / sum;
#pragma unroll
            for (int mj = 0; mj < 4; ++mj) {
                int col = lr + mj * 16;
                int byteoff = (row * 128 + col * 2) ^ ((row & 7) << 4);
                *(unsigned short*)((char*)ps[wave] + byteoff) = f2bf(e[mj] * rinv);
            }
        }
    }
    // no barrier needed: ps/vs are per-wave (lgkmcnt orders within wave)

    // ---- 8. O = P V ----
    f32x4 oacc[4][2] = {};
#pragma unroll
    for (int ks = 0; ks < 2; ++ks) {
        bf16x8_t pf[4];
#pragma unroll
        for (int ni = 0; ni < 4; ++ni) {
            int row = ni * 16 + lr;
            int byteoff = (row * 128 + (ks * 32 + g * 8) * 2) ^ ((row & 7) << 4);
            pf[ni] = *(const bf16x8_t*)((char*)ps[wave] + byteoff);
        }
        bf16x8_t vf[2];
#pragma unroll
        for (int dj = 0; dj < 2; ++dj) {
#pragma unroll
            for (int j = 0; j < 8; ++j)
                vf[dj][j] = (short)vs[wave][(ks * 32 + g * 8 + j) * 40 + lr + dj * 16];
        }
#pragma unroll
        for (int ni = 0; ni < 4; ++ni)
#pragma unroll
            for (int dj = 0; dj < 2; ++dj)
                oacc[ni][dj] = __builtin_amdgcn_mfma_f32_16x16x32_bf16(
                    pf[ni], vf[dj], oacc[ni][dj], 0, 0, 0);
    }

    // ---- 9. store O (rows < 49) ----
#pragma unroll
    for (int ni = 0; ni < 4; ++ni) {
#pragma unroll
        for (int q = 0; q < 4; ++q) {
            int row = ni * 16 + g * 4 + q;
            if (row < NTOK) {
#pragma unroll
                for (int dj = 0; dj < 2; ++dj)
                    o[((size_t)w * NTOK + row) * C_DIM + h * HDIM + lr + dj * 16] =
                        f2bf(oacc[ni][dj][q]);
            }
        }
    }
}

// ---------------------------------------------------------------------------
extern "C" void kernel_launch(void* const* d_in, const int* in_sizes, int n_in,
                              void* d_out, int out_size, void* d_ws, size_t ws_size,
                              hipStream_t stream)
{
    const float* x       = (const float*)d_in[0];
    const float* q_w     = (const float*)d_in[1];
    const float* kv_w    = (const float*)d_in[2];
    const float* proj_w  = (const float*)d_in[3];
    const float* proj_b  = (const float*)d_in[4];
    const float* fc1_w   = (const float*)d_in[5];
    const float* fc1_b   = (const float*)d_in[6];
    const float* fc2_w   = (const float*)d_in[7];
    const float* fc2_b   = (const float*)d_in[8];
    const float* n1g     = (const float*)d_in[9];
    const float* n1b     = (const float*)d_in[10];
    const float* n2g     = (const float*)d_in[11];
    const float* n2b     = (const float*)d_in[12];
    const float* ls1     = (const float*)d_in[13];
    const float* ls2     = (const float*)d_in[14];
    const float* btable  = (const float*)d_in[15];

    float* out = (float*)d_out;
    char*  ws  = (char*)d_ws;

    // Workspace layout:
    //   0          qkv bf16 (57.8 MB) -> hidden bf16 (77 MB)
    //   115605504  xw bf16 (19.3 MB) -> obuf bf16
    //   134873088  hbuf bf16 (19.3 MB)
    //   154140672  weights bf16 (7.08 MB)
    //   161218560  biasmat16 (61440 B)
    unsigned short* qkvbuf = (unsigned short*)(ws);
    unsigned short* hidden = (unsigned short*)(ws);
    unsigned short* xw     = (unsigned short*)(ws + 115605504);
    unsigned short* obuf   = xw;
    unsigned short* hbuf   = (unsigned short*)(ws + 134873088);
    unsigned short* wqkv   = (unsigned short*)(ws + 154140672);
    unsigned short* wproj  = wqkv + 442368;
    unsigned short* wfc1   = wproj + 147456;
    unsigned short* wfc2   = wfc1 + 589824;
    unsigned short* biasmat16 = (unsigned short*)(ws + 161218560);

    // 0. weights -> bf16 ; relative-position bias matrix (bf16, stride 52)
    convert_weights_kernel<<<1728, 256, 0, stream>>>(q_w, kv_w, proj_w, fc1_w, fc2_w, wqkv);
    bias_precompute_kernel<<<113, 256, 0, stream>>>(btable, biasmat16);

    // 1. LN1 + window partition -> xw (bf16)
    ln_kernel<true, true><<<(T_TOK * 64 + 255) / 256, 256, 0, stream>>>(x, n1g, n1b, xw);

    // 2. fused qkv = xw @ [q_w;kv_w]^T  (M=25088, N=1152, K=384)
    gemm_bf16_kernel<0, true, false><<<dim3(T_TOK / 128, 1152 / 128), 256, 0, stream>>>(
        xw, wqkv, nullptr, nullptr, nullptr, qkvbuf, T_TOK, 1152, C_DIM);

    // 3. MFMA windowed attention -> obuf (bf16); 2 windows x 1 head per block
    attn_mfma_kernel<<<(NWIN / 2) * NHEADS, 128, 0, stream>>>(qkvbuf, biasmat16, obuf);

    // 4. proj + window reverse + residual + ls1 -> d_out (fp32, token layout)
    gemm_bf16_kernel<3, false, true><<<dim3(T_TOK / 128, C_DIM / 128), 256, 0, stream>>>(
        obuf, wproj, proj_b, x, ls1, out, T_TOK, C_DIM, C_DIM);

    // 5. LN2 -> hbuf (bf16)
    ln_kernel<false, true><<<(T_TOK * 64 + 255) / 256, 256, 0, stream>>>(out, n2g, n2b, hbuf);

    // 6. hidden = gelu(hbuf @ fc1_w^T + fc1_b) -> bf16 (N=1536)
    gemm_bf16_kernel<2, true, false><<<dim3(T_TOK / 128, 1536 / 128), 256, 0, stream>>>(
        hbuf, wfc1, fc1_b, nullptr, nullptr, hidden, T_TOK, 1536, C_DIM);

    // 7. d_out = x1 + ls2 * (hidden @ fc2_w^T + fc2_b)  (K=1536)
    gemm_bf16_kernel<3, false, false><<<dim3(T_TOK / 128, C_DIM / 128), 256, 0, stream>>>(
        hidden, wfc2, fc2_b, out, ls2, out, T_TOK, C_DIM, 1536);
}